// Round 11
// baseline (136.359 us; speedup 1.0000x reference)
//
#include <hip/hip_runtime.h>
#include <hip/hip_bf16.h>

constexpr int BB = 32;    // batch
constexpr int TT = 512;   // decode steps
constexpr int NN = 512;   // nodes
constexpr int DD = 256;   // model dim
constexpr int HH = 8;     // heads
constexpr int DH = 32;    // head dim
#define NEG_INF (-1e9f)

typedef __attribute__((ext_vector_type(8))) short bf16x8;
typedef __attribute__((ext_vector_type(4))) float f32x4;

__device__ inline ushort f2bf(float x) {
    union { float f; unsigned u; } c; c.f = x;
    unsigned u = c.u + 0x7fffu + ((c.u >> 16) & 1u);  // RNE
    return (ushort)(u >> 16);
}
__device__ inline uint pk2t(float a, float b) {  // truncating pack
    return __builtin_amdgcn_perm(__float_as_uint(b), __float_as_uint(a),
                                 0x07060302u);
}
__device__ inline float ulo(uint u) {
    union { uint u; float f; } c; c.u = u << 16; return c.f;
}
__device__ inline float uhi(uint u) {
    union { uint u; float f; } c; c.u = u & 0xffff0000u; return c.f;
}
__device__ inline float fast_tanh10(float x) {
    x = fminf(fmaxf(x, -20.f), 20.f);
    float e2 = __expf(2.f * x);
    return 10.f * (1.f - 2.f / (e2 + 1.f));
}

// ---------------------------------------------------------------------------
// prep_all: [0,256) emb cvt+partials | [256,576) weight transposes |
//           [576,1600) mask bit-pack
__global__ __launch_bounds__(256) void prep_all_k(
    const float* __restrict__ emb, ushort* __restrict__ embB,
    float* __restrict__ partial, const float* __restrict__ Wn,
    const float* __restrict__ Ws, const float* __restrict__ Wo,
    ushort* __restrict__ WnT, ushort* __restrict__ WsT,
    ushort* __restrict__ WoT, const int* __restrict__ mask,
    uint* __restrict__ mbt) {
    int j = blockIdx.x;
    int tid = threadIdx.x;
    if (j < 256) {
        int b = j >> 3, part = j & 7, d = tid;
        const float* eb = emb + ((size_t)b * NN + part * 64) * DD + d;
        ushort* ob = embB + ((size_t)b * NN + part * 64) * DD + d;
        float s = 0.f;
        #pragma unroll 4
        for (int i = 0; i < 64; i++) {
            float v = eb[(size_t)i * DD];
            s += v;
            ob[(size_t)i * DD] = f2bf(v);
        }
        partial[((size_t)b * 8 + part) * DD + d] = s;
    } else if (j < 576) {
        __shared__ float t[32][33];
        int g = j - 256;
        int gx = g % 40, gy = g / 40;
        const float* W;
        ushort* WT;
        int NC, xb;
        if (gx < 24)      { W = Wn; WT = WnT; NC = 768; xb = gx; }
        else if (gx < 32) { W = Ws; WT = WsT; NC = 256; xb = gx - 24; }
        else              { W = Wo; WT = WoT; NC = 256; xb = gx - 32; }
        int tx = tid & 31, ty = tid >> 5;
        int x = xb * 32 + tx;
        int y0 = gy * 32;
        #pragma unroll
        for (int i = 0; i < 4; i++)
            t[ty + i * 8][tx] = W[(size_t)(y0 + ty + i * 8) * NC + x];
        __syncthreads();
        #pragma unroll
        for (int i = 0; i < 4; i++)
            WT[(size_t)(xb * 32 + ty + i * 8) * 256 + y0 + tx] =
                f2bf(t[tx][ty + i * 8]);
    } else {
        int idx = (j - 576) * 256 + tid;
        int row = idx >> 4, w = idx & 15;
        const int* mr = mask + (size_t)row * NN + w;
        uint u = 0;
        #pragma unroll
        for (int c = 0; c < 32; c++) u |= (uint)(mr[c * 16] != 0) << c;
        mbt[idx] = u;
    }
}

// ctx = mean @ W_fixed; grid BB
__global__ __launch_bounds__(256) void ctx_mm_k(const float* __restrict__ partial,
                                                const float* __restrict__ Wf,
                                                float* __restrict__ ctx) {
    int b = blockIdx.x, d = threadIdx.x;
    __shared__ float ms[256];
    float s = 0.f;
    #pragma unroll
    for (int p = 0; p < 8; p++) s += partial[((size_t)b * 8 + p) * DD + d];
    ms[d] = s * (1.0f / NN);
    __syncthreads();
    float acc = 0.f;
    #pragma unroll 8
    for (int k = 0; k < 256; k++) acc += ms[k] * Wf[(size_t)k * DD + d];
    ctx[(size_t)b * DD + d] = acc;
}

// ---------------------------------------------------------------------------
// gemm3: BM=128 x BN=64 x BK=64, 24KB LDS (6 blocks/CU), 4 k-iters.
// Wave owns 32 rows (2 row-groups). Swizzle: write slot^(row&7), read
// slot^(lo&7) (row&7 == lo&7 on all read rows).
// TASK 0: j<1536 -> K1 (proj: gkT/vTp/lk); j>=1536 -> K2 (gq, gather+bias).
// TASK 1: K4 (glimpse = heads @ Wo).
template <int TASK>
__global__ __launch_bounds__(256) void gemm3_k(
    const ushort* __restrict__ A0, const ushort* __restrict__ WT0,
    const ushort* __restrict__ WT1, ushort* __restrict__ O0,
    ushort* __restrict__ O1, ushort* __restrict__ O2,
    ushort* __restrict__ O3, const float* __restrict__ ctx,
    const int* __restrict__ cur) {
    int j = blockIdx.x;
    bool k2 = (TASK == 0) && (j >= 1536);
    int jj = k2 ? j - 1536 : j;
    int bx = jj & 127, by = jj >> 7;
    int row0 = bx * 128, col0 = by * 64;
    int tid = threadIdx.x;
    int w = tid >> 6, l = tid & 63;
    int lo = l & 15, hi = l >> 4;

    __shared__ ushort As[128 * 64];  // 16KB, rows 128B
    __shared__ ushort Bs[64 * 64];   // 8KB,  rows 128B

    const ushort* WT = k2 ? WT1 : WT0;
    const f32x4 zero = {0.f, 0.f, 0.f, 0.f};
    f32x4 acc[2][4] = {{zero, zero, zero, zero}, {zero, zero, zero, zero}};

    for (int kk = 0; kk < 4; kk++) {
        if (kk) __syncthreads();
        // stage A half-panel: 1024 x 16B units
        #pragma unroll
        for (int i = 0; i < 4; i++) {
            int u = i * 256 + tid;
            int row = u >> 3, slot = u & 7;
            int arow = row0 + row;
            const ushort* ap;
            if (k2) {
                int b = arow >> 9;
                ap = A0 + ((size_t)(b * NN + cur[arow])) * DD;
            } else {
                ap = A0 + (size_t)arow * DD;
            }
            uint4 v = *(const uint4*)(ap + kk * 64 + slot * 8);
            *(uint4*)((char*)As + row * 128 + ((slot ^ (row & 7)) << 4)) = v;
        }
        // stage B tile: 512 x 16B units
        #pragma unroll
        for (int i = 0; i < 2; i++) {
            int u = i * 256 + tid;
            int row = u >> 3, slot = u & 7;
            uint4 v = *(const uint4*)(WT + (size_t)(col0 + row) * 256 + kk * 64 + slot * 8);
            *(uint4*)((char*)Bs + row * 128 + ((slot ^ (row & 7)) << 4)) = v;
        }
        __syncthreads();
        #pragma unroll
        for (int ks = 0; ks < 2; ks++) {
            int sx = ((ks * 4 + hi) ^ (lo & 7)) << 4;
            bf16x8 af0 = *(const bf16x8*)((char*)As + (w * 32 + lo) * 128 + sx);
            bf16x8 af1 = *(const bf16x8*)((char*)As + (w * 32 + 16 + lo) * 128 + sx);
            #pragma unroll
            for (int c = 0; c < 4; c++) {
                bf16x8 bf = *(const bf16x8*)((char*)Bs + (c * 16 + lo) * 128 + sx);
                acc[0][c] = __builtin_amdgcn_mfma_f32_16x16x32_bf16(af0, bf, acc[0][c], 0, 0, 0);
                acc[1][c] = __builtin_amdgcn_mfma_f32_16x16x32_bf16(af1, bf, acc[1][c], 0, 0, 0);
            }
        }
    }

    #pragma unroll
    for (int rg = 0; rg < 2; rg++) {
        int rw0 = row0 + w * 32 + rg * 16;
        int bb = rw0 >> 9;
        #pragma unroll
        for (int c = 0; c < 4; c++) {
            int col = col0 + c * 16 + lo;
            float v[4];
            #pragma unroll
            for (int r = 0; r < 4; r++) v[r] = acc[rg][c][r];
            if constexpr (TASK == 0) {
                if (k2) {
                    float bv = ctx[(size_t)bb * DD + col];
                    #pragma unroll
                    for (int r = 0; r < 4; r++)
                        O3[(size_t)(rw0 + 4 * hi + r) * DD + col] = f2bf(v[r] + bv);
                } else if (col < 256) {
                    int head = col >> 5, dh = col & 31;
                    #pragma unroll
                    for (int r = 0; r < 4; r++) {
                        int n = (rw0 + 4 * hi + r) & (NN - 1);
                        O0[(((size_t)(bb * HH + head) * NN + n) << 5) + dh] = f2bf(v[r]);
                    }
                } else if (col < 512) {
                    int cc = col - 256;
                    int bhv = bb * HH + (cc >> 5);
                    int dh = cc & 31;
                    int n0 = (rw0 + 4 * hi) & (NN - 1);
                    int m = n0 >> 2;
                    int p_ = m >> 3, s_ = (m >> 2) & 1, g_ = m & 3;
                    int n0p = (8 * p_ + 2 * g_ + s_) << 2;
                    ushort4 uv = {f2bf(v[0]), f2bf(v[1]), f2bf(v[2]), f2bf(v[3])};
                    *(ushort4*)(O1 + ((size_t)bhv * DH + dh) * NN + n0p) = uv;
                } else {
                    #pragma unroll
                    for (int r = 0; r < 4; r++)
                        O2[(size_t)(rw0 + 4 * hi + r) * 256 + (col - 512)] = f2bf(v[r]);
                }
            } else {
                #pragma unroll
                for (int r = 0; r < 4; r++)
                    O0[(size_t)(rw0 + 4 * hi + r) * DD + col] = f2bf(v[r]);
            }
        }
    }
}

// ---------------------------------------------------------------------------
// K3: LDS-staged swapped-operand attention (verified r8-r10).
__global__ __launch_bounds__(256) void attn8_k(
    const ushort* __restrict__ gq, const ushort* __restrict__ gkT,
    const ushort* __restrict__ vTp, const uint* __restrict__ mbt,
    ushort* __restrict__ headsB) {
    int j = blockIdx.x;
    int bh = j & 255, half = j >> 8;
    int b = bh >> 3, h = bh & 7;
    int tid = threadIdx.x;
    int w = tid >> 6, l = tid & 63;
    int lo = l & 15, hi = l >> 4;

    __shared__ ushort Ks[16384];
    __shared__ ushort Vs[16384];
    __shared__ ushort OT[4][16][40];

    {
        const uint4* src = (const uint4*)(gkT + (size_t)bh * (NN * DH));
        #pragma unroll
        for (int i = 0; i < 8; i++) {
            int u = i * 256 + tid;
            uint4 v = src[u];
            int G = u << 4;
            int a = G ^ (((G >> 6) & 7) << 4);
            *(uint4*)((char*)Ks + a) = v;
        }
    }
    {
        const uint4* src = (const uint4*)(vTp + (size_t)bh * (DH * NN));
        #pragma unroll
        for (int i = 0; i < 8; i++) {
            int u = i * 256 + tid;
            uint4 v = src[u];
            int G = u << 4;
            int a = G ^ (((G >> 10) & 7) << 4);
            *(uint4*)((char*)Vs + a) = v;
        }
    }
    __syncthreads();

    const f32x4 zero = {0.f, 0.f, 0.f, 0.f};
    const bf16x8 ones = {(short)0x3F80, (short)0x3F80, (short)0x3F80,
                         (short)0x3F80, (short)0x3F80, (short)0x3F80,
                         (short)0x3F80, (short)0x3F80};
    const float sc = 0.17677669529663687f;  // 1/sqrt(32)
    int q0 = half * 256;
    int kswz = (lo & 7) << 4;

    for (int qc2 = 0; qc2 < 4; qc2++) {
        int t0 = q0 + qc2 * 64 + w * 16;
        bf16x8 qf = *(const bf16x8*)(gq + ((size_t)(b * TT + t0 + lo)) * DD + h * DH + hi * 8);
        uint4 mq = *(const uint4*)(mbt + ((size_t)(b * TT + t0 + lo)) * 16 + 4 * hi);

        f32x4 o0 = zero, o1 = zero, osum = zero;

        #pragma unroll
        for (int p = 0; p < 16; p++) {
            int n0 = 32 * p + lo;
            bf16x8 kf0 = *(const bf16x8*)((char*)Ks + ((n0 * 64 + hi * 16) ^ kswz));
            bf16x8 kf1 = *(const bf16x8*)((char*)Ks + (((n0 + 16) * 64 + hi * 16) ^ kswz));
            f32x4 s0 = __builtin_amdgcn_mfma_f32_16x16x32_bf16(kf0, qf, zero, 0, 0, 0);
            f32x4 s1 = __builtin_amdgcn_mfma_f32_16x16x32_bf16(kf1, qf, zero, 0, 0, 0);
            union { bf16x8 v; uint u[4]; } pf;
            {
                const int c = 2 * p;
                float e0 = ((mq.x >> c) & 1u) ? __expf(s0[0] * sc) : 0.f;
                float e1 = ((mq.y >> c) & 1u) ? __expf(s0[1] * sc) : 0.f;
                float e2 = ((mq.z >> c) & 1u) ? __expf(s0[2] * sc) : 0.f;
                float e3 = ((mq.w >> c) & 1u) ? __expf(s0[3] * sc) : 0.f;
                pf.u[0] = pk2t(e0, e1);
                pf.u[1] = pk2t(e2, e3);
            }
            {
                const int c = 2 * p + 1;
                float e0 = ((mq.x >> c) & 1u) ? __expf(s1[0] * sc) : 0.f;
                float e1 = ((mq.y >> c) & 1u) ? __expf(s1[1] * sc) : 0.f;
                float e2 = ((mq.z >> c) & 1u) ? __expf(s1[2] * sc) : 0.f;
                float e3 = ((mq.w >> c) & 1u) ? __expf(s1[3] * sc) : 0.f;
                pf.u[2] = pk2t(e0, e1);
                pf.u[3] = pk2t(e2, e3);
            }
            int vo = (32 * p + 8 * hi) * 2;
            bf16x8 va0 = *(const bf16x8*)((char*)Vs + (((lo << 10) + vo) ^ kswz));
            bf16x8 va1 = *(const bf16x8*)((char*)Vs + ((((lo + 16) << 10) + vo) ^ kswz));
            o0 = __builtin_amdgcn_mfma_f32_16x16x32_bf16(va0, pf.v, o0, 0, 0, 0);
            o1 = __builtin_amdgcn_mfma_f32_16x16x32_bf16(va1, pf.v, o1, 0, 0, 0);
            osum = __builtin_amdgcn_mfma_f32_16x16x32_bf16(ones, pf.v, osum, 0, 0, 0);
        }

        float inv = 1.0f / fmaxf(osum[0], 1e-30f);

        #pragma unroll
        for (int r = 0; r < 4; r++) {
            OT[w][lo][4 * hi + r] = (ushort)(__float_as_uint(o0[r] * inv) >> 16);
            OT[w][lo][16 + 4 * hi + r] = (ushort)(__float_as_uint(o1[r] * inv) >> 16);
        }
        bf16x8 ov = *(const bf16x8*)(&OT[w][lo][hi * 8]);
        *(bf16x8*)(headsB + ((size_t)(b * TT + t0 + lo)) * DD + h * DH + hi * 8) = ov;
    }
}

// ---------------------------------------------------------------------------
// K5: LDS-staged pointer logits, 32 q-rows/block (512 blocks), fixed max=10.
__global__ __launch_bounds__(256) void logits6_k(
    const ushort* __restrict__ glimpse, const ushort* __restrict__ lk,
    const uint* __restrict__ mbt, float* __restrict__ out) {
    int j = blockIdx.x;  // 32 b x 16 tc
    int b = j & 31;
    int t0 = (j >> 5) * 32;
    int tid = threadIdx.x;
    int w = tid >> 6, l = tid & 63;
    int lo = l & 15, hi = l >> 4;

    __shared__ ushort Ls[64 * 256];  // 32KB, rows 512B, swz (row&7)<<4
    __shared__ float reds[4][2][16];

    bf16x8 af0[8], af1[8];
    {
        const ushort* g0 = glimpse + ((size_t)(b * TT + t0 + lo)) * DD + hi * 8;
        const ushort* g1 = glimpse + ((size_t)(b * TT + t0 + 16 + lo)) * DD + hi * 8;
        #pragma unroll
        for (int ks = 0; ks < 8; ks++) {
            af0[ks] = *(const bf16x8*)(g0 + ks * 32);
            af1[ks] = *(const bf16x8*)(g1 + ks * 32);
        }
    }
    uint mw0[4], mw1[4];
    #pragma unroll
    for (int r = 0; r < 4; r++) {
        mw0[r] = mbt[((size_t)(b * TT + t0 + 4 * hi + r)) * 16 + lo];
        mw1[r] = mbt[((size_t)(b * TT + t0 + 16 + 4 * hi + r)) * 16 + lo];
    }

    const f32x4 zero = {0.f, 0.f, 0.f, 0.f};
    const ushort* lkb = lk + (size_t)b * NN * DD;
    float sum0[4] = {0.f, 0.f, 0.f, 0.f}, sum1[4] = {0.f, 0.f, 0.f, 0.f};
    uint tuA[8], tuB[8], tuC[8], tuD[8];
    int swz = (lo & 7) << 4;

    #pragma unroll
    for (int it = 0; it < 8; it++) {
        if (it) __syncthreads();
        #pragma unroll
        for (int i = 0; i < 8; i++) {
            int u = i * 256 + tid;
            int row = u >> 5, slot = u & 31;
            uint4 v = *(const uint4*)(lkb + (size_t)(it * 64 + row) * 256 + slot * 8);
            *(uint4*)((char*)Ls + row * 512 + ((slot << 4) ^ ((row & 7) << 4))) = v;
        }
        __syncthreads();
        int c = it * 4 + w;
        f32x4 a0 = zero, a1 = zero;
        #pragma unroll
        for (int ks = 0; ks < 8; ks++) {
            bf16x8 bf = *(const bf16x8*)((char*)Ls + (w * 16 + lo) * 512 +
                                         (((ks * 4 + hi) << 4) ^ swz));
            a0 = __builtin_amdgcn_mfma_f32_16x16x32_bf16(af0[ks], bf, a0, 0, 0, 0);
            a1 = __builtin_amdgcn_mfma_f32_16x16x32_bf16(af1[ks], bf, a1, 0, 0, 0);
        }
        float t0v[4], t1v[4];
        #pragma unroll
        for (int r = 0; r < 4; r++) {
            t0v[r] = fast_tanh10(a0[r] * 0.0625f);
            t1v[r] = fast_tanh10(a1[r] * 0.0625f);
            sum0[r] += ((mw0[r] >> c) & 1u) ? __expf(t0v[r] - 10.f) : 0.f;
            sum1[r] += ((mw1[r] >> c) & 1u) ? __expf(t1v[r] - 10.f) : 0.f;
        }
        tuA[it] = pk2t(t0v[0], t0v[1]);
        tuB[it] = pk2t(t0v[2], t0v[3]);
        tuC[it] = pk2t(t1v[0], t1v[1]);
        tuD[it] = pk2t(t1v[2], t1v[3]);
    }

    #pragma unroll
    for (int r = 0; r < 4; r++) {
        #pragma unroll
        for (int o = 1; o < 16; o <<= 1) {
            sum0[r] += __shfl_xor(sum0[r], o);
            sum1[r] += __shfl_xor(sum1[r], o);
        }
    }
    if (lo == 0) {
        #pragma unroll
        for (int r = 0; r < 4; r++) {
            reds[w][0][4 * hi + r] = sum0[r];
            reds[w][1][4 * hi + r] = sum1[r];
        }
    }
    __syncthreads();
    float lse0[4], lse1[4];
    #pragma unroll
    for (int r = 0; r < 4; r++) {
        int row = 4 * hi + r;
        lse0[r] = 10.f + __logf(fmaxf(reds[0][0][row] + reds[1][0][row] +
                                      reds[2][0][row] + reds[3][0][row], 1e-37f));
        lse1[r] = 10.f + __logf(fmaxf(reds[0][1][row] + reds[1][1][row] +
                                      reds[2][1][row] + reds[3][1][row], 1e-37f));
    }

    #pragma unroll
    for (int it = 0; it < 8; it++) {
        int c = it * 4 + w;
        float v0[4] = {ulo(tuA[it]), uhi(tuA[it]), ulo(tuB[it]), uhi(tuB[it])};
        float v1[4] = {ulo(tuC[it]), uhi(tuC[it]), ulo(tuD[it]), uhi(tuD[it])};
        #pragma unroll
        for (int r = 0; r < 4; r++) {
            float ov0 = ((mw0[r] >> c) & 1u) ? v0[r] - lse0[r] : NEG_INF - lse0[r];
            float ov1 = ((mw1[r] >> c) & 1u) ? v1[r] - lse1[r] : NEG_INF - lse1[r];
            out[((size_t)(b * TT + t0 + 4 * hi + r)) * NN + c * 16 + lo] = ov0;
            out[((size_t)(b * TT + t0 + 16 + 4 * hi + r)) * NN + c * 16 + lo] = ov1;
        }
    }
}

// ---------------------------------------------------------------------------
extern "C" void kernel_launch(void* const* d_in, const int* in_sizes, int n_in,
                              void* d_out, int out_size, void* d_ws,
                              size_t ws_size, hipStream_t stream) {
    const float* emb = (const float*)d_in[0];
    const int* cur   = (const int*)d_in[1];
    const int* mask  = (const int*)d_in[2];
    const float* Wn  = (const float*)d_in[3];
    const float* Wf  = (const float*)d_in[4];
    const float* Ws  = (const float*)d_in[5];
    const float* Wo  = (const float*)d_in[6];
    float* out = (float*)d_out;

    const size_t SLABE = (size_t)BB * NN * DD;
    ushort* embB     = (ushort*)d_ws;
    ushort* gkT      = embB + SLABE;     // [bh][n][32]
    ushort* vTp      = gkT + SLABE;      // [bh][dh][n''] pre-permuted
    ushort* lkb      = vTp + SLABE;      // [b*N+n][256]
    ushort* gq       = lkb + SLABE;      // [b*T+t][256]
    ushort* headsB   = gq + SLABE;
    ushort* glimpseB = headsB + SLABE;
    ushort* WnT      = glimpseB + SLABE;
    ushort* WsT      = WnT + 768 * 256;
    ushort* WoT      = WsT + 256 * 256;
    uint*   mbt      = (uint*)(WoT + 256 * 256);
    float*  ctx      = (float*)(mbt + (size_t)BB * TT * 16);
    float*  partial  = ctx + (size_t)BB * DD;

    prep_all_k<<<1600, 256, 0, stream>>>(emb, embB, partial, Wn, Ws, Wo,
                                         WnT, WsT, WoT, mask, mbt);
    ctx_mm_k<<<BB, 256, 0, stream>>>(partial, Wf, ctx);
    // K1 (1536 blocks) + K2 (512 blocks) fused
    gemm3_k<0><<<2048, 256, 0, stream>>>(embB, WnT, WsT, gkT, vTp, lkb, gq,
                                         ctx, cur);
    attn8_k<<<512, 256, 0, stream>>>(gq, gkT, vTp, mbt, headsB);
    // K4
    gemm3_k<1><<<512, 256, 0, stream>>>(headsB, WoT, nullptr, glimpseB,
                                        nullptr, nullptr, nullptr, nullptr,
                                        nullptr);
    logits6_k<<<512, 256, 0, stream>>>(glimpseB, lkb, mbt, out);
}

// Round 12
// 126.674 us; speedup vs baseline: 1.0765x; 1.0765x over previous
//
#include <hip/hip_runtime.h>
#include <hip/hip_bf16.h>

constexpr int BB = 32;    // batch
constexpr int TT = 512;   // decode steps
constexpr int NN = 512;   // nodes
constexpr int DD = 256;   // model dim
constexpr int HH = 8;     // heads
constexpr int DH = 32;    // head dim
#define NEG_INF (-1e9f)

typedef __attribute__((ext_vector_type(8))) short bf16x8;
typedef __attribute__((ext_vector_type(4))) float f32x4;

__device__ inline ushort f2bf(float x) {
    union { float f; unsigned u; } c; c.f = x;
    unsigned u = c.u + 0x7fffu + ((c.u >> 16) & 1u);  // RNE
    return (ushort)(u >> 16);
}
__device__ inline uint pk2t(float a, float b) {  // truncating pack
    return __builtin_amdgcn_perm(__float_as_uint(b), __float_as_uint(a),
                                 0x07060302u);
}
__device__ inline ushort tr16(float x) { return (ushort)(__float_as_uint(x) >> 16); }
__device__ inline float bf2f(ushort u) {
    union { uint u; float f; } c; c.u = (uint)u << 16; return c.f;
}
__device__ inline float fast_tanh10(float x) {
    x = fminf(fmaxf(x, -20.f), 20.f);
    float e2 = __expf(2.f * x);
    return 10.f * (1.f - 2.f / (e2 + 1.f));
}

// ---------------------------------------------------------------------------
// prep_all: [0,256) emb cvt+partials | [256,576) weight transposes |
//           [576,1600) mask bit-pack
__global__ __launch_bounds__(256) void prep_all_k(
    const float* __restrict__ emb, ushort* __restrict__ embB,
    float* __restrict__ partial, const float* __restrict__ Wn,
    const float* __restrict__ Ws, const float* __restrict__ Wo,
    ushort* __restrict__ WnT, ushort* __restrict__ WsT,
    ushort* __restrict__ WoT, const int* __restrict__ mask,
    uint* __restrict__ mbt) {
    int j = blockIdx.x;
    int tid = threadIdx.x;
    if (j < 256) {
        int b = j >> 3, part = j & 7, d = tid;
        const float* eb = emb + ((size_t)b * NN + part * 64) * DD + d;
        ushort* ob = embB + ((size_t)b * NN + part * 64) * DD + d;
        float s = 0.f;
        #pragma unroll 4
        for (int i = 0; i < 64; i++) {
            float v = eb[(size_t)i * DD];
            s += v;
            ob[(size_t)i * DD] = f2bf(v);
        }
        partial[((size_t)b * 8 + part) * DD + d] = s;
    } else if (j < 576) {
        __shared__ float t[32][33];
        int g = j - 256;
        int gx = g % 40, gy = g / 40;
        const float* W;
        ushort* WT;
        int NC, xb;
        if (gx < 24)      { W = Wn; WT = WnT; NC = 768; xb = gx; }
        else if (gx < 32) { W = Ws; WT = WsT; NC = 256; xb = gx - 24; }
        else              { W = Wo; WT = WoT; NC = 256; xb = gx - 32; }
        int tx = tid & 31, ty = tid >> 5;
        int x = xb * 32 + tx;
        int y0 = gy * 32;
        #pragma unroll
        for (int i = 0; i < 4; i++)
            t[ty + i * 8][tx] = W[(size_t)(y0 + ty + i * 8) * NC + x];
        __syncthreads();
        #pragma unroll
        for (int i = 0; i < 4; i++)
            WT[(size_t)(xb * 32 + ty + i * 8) * 256 + y0 + tx] =
                f2bf(t[tx][ty + i * 8]);
    } else {
        int idx = (j - 576) * 256 + tid;
        int row = idx >> 4, w = idx & 15;
        const int* mr = mask + (size_t)row * NN + w;
        uint u = 0;
        #pragma unroll
        for (int c = 0; c < 32; c++) u |= (uint)(mr[c * 16] != 0) << c;
        mbt[idx] = u;
    }
}

// ctx = mean @ W_fixed; grid BB
__global__ __launch_bounds__(256) void ctx_mm_k(const float* __restrict__ partial,
                                                const float* __restrict__ Wf,
                                                float* __restrict__ ctx) {
    int b = blockIdx.x, d = threadIdx.x;
    __shared__ float ms[256];
    float s = 0.f;
    #pragma unroll
    for (int p = 0; p < 8; p++) s += partial[((size_t)b * 8 + p) * DD + d];
    ms[d] = s * (1.0f / NN);
    __syncthreads();
    float acc = 0.f;
    #pragma unroll 8
    for (int k = 0; k < 256; k++) acc += ms[k] * Wf[(size_t)k * DD + d];
    ctx[(size_t)b * DD + d] = acc;
}

// ---------------------------------------------------------------------------
// gemm3: BM=128 x BN=64 x BK=64, 24KB LDS, 4 k-iters (verified r11).
// TASK 0: j<1536 -> K1 (proj -> gkT/vTp/lk); j>=1536 -> K2 (gq).
// TASK 1: K4 (glimpse = heads @ Wo).
template <int TASK>
__global__ __launch_bounds__(256) void gemm3_k(
    const ushort* __restrict__ A0, const ushort* __restrict__ WT0,
    const ushort* __restrict__ WT1, ushort* __restrict__ O0,
    ushort* __restrict__ O1, ushort* __restrict__ O2,
    ushort* __restrict__ O3, const float* __restrict__ ctx,
    const int* __restrict__ cur) {
    int j = blockIdx.x;
    bool k2 = (TASK == 0) && (j >= 1536);
    int jj = k2 ? j - 1536 : j;
    int bx = jj & 127, by = jj >> 7;
    int row0 = bx * 128, col0 = by * 64;
    int tid = threadIdx.x;
    int w = tid >> 6, l = tid & 63;
    int lo = l & 15, hi = l >> 4;

    __shared__ ushort As[128 * 64];  // 16KB
    __shared__ ushort Bs[64 * 64];   // 8KB

    const ushort* WT = k2 ? WT1 : WT0;
    const f32x4 zero = {0.f, 0.f, 0.f, 0.f};
    f32x4 acc[2][4] = {{zero, zero, zero, zero}, {zero, zero, zero, zero}};

    for (int kk = 0; kk < 4; kk++) {
        if (kk) __syncthreads();
        #pragma unroll
        for (int i = 0; i < 4; i++) {
            int u = i * 256 + tid;
            int row = u >> 3, slot = u & 7;
            int arow = row0 + row;
            const ushort* ap;
            if (k2) {
                int b = arow >> 9;
                ap = A0 + ((size_t)(b * NN + cur[arow])) * DD;
            } else {
                ap = A0 + (size_t)arow * DD;
            }
            uint4 v = *(const uint4*)(ap + kk * 64 + slot * 8);
            *(uint4*)((char*)As + row * 128 + ((slot ^ (row & 7)) << 4)) = v;
        }
        #pragma unroll
        for (int i = 0; i < 2; i++) {
            int u = i * 256 + tid;
            int row = u >> 3, slot = u & 7;
            uint4 v = *(const uint4*)(WT + (size_t)(col0 + row) * 256 + kk * 64 + slot * 8);
            *(uint4*)((char*)Bs + row * 128 + ((slot ^ (row & 7)) << 4)) = v;
        }
        __syncthreads();
        #pragma unroll
        for (int ks = 0; ks < 2; ks++) {
            int sx = ((ks * 4 + hi) ^ (lo & 7)) << 4;
            bf16x8 af0 = *(const bf16x8*)((char*)As + (w * 32 + lo) * 128 + sx);
            bf16x8 af1 = *(const bf16x8*)((char*)As + (w * 32 + 16 + lo) * 128 + sx);
            #pragma unroll
            for (int c = 0; c < 4; c++) {
                bf16x8 bf = *(const bf16x8*)((char*)Bs + (c * 16 + lo) * 128 + sx);
                acc[0][c] = __builtin_amdgcn_mfma_f32_16x16x32_bf16(af0, bf, acc[0][c], 0, 0, 0);
                acc[1][c] = __builtin_amdgcn_mfma_f32_16x16x32_bf16(af1, bf, acc[1][c], 0, 0, 0);
            }
        }
    }

    #pragma unroll
    for (int rg = 0; rg < 2; rg++) {
        int rw0 = row0 + w * 32 + rg * 16;
        int bb = rw0 >> 9;
        #pragma unroll
        for (int c = 0; c < 4; c++) {
            int col = col0 + c * 16 + lo;
            float v[4];
            #pragma unroll
            for (int r = 0; r < 4; r++) v[r] = acc[rg][c][r];
            if constexpr (TASK == 0) {
                if (k2) {
                    float bv = ctx[(size_t)bb * DD + col];
                    #pragma unroll
                    for (int r = 0; r < 4; r++)
                        O3[(size_t)(rw0 + 4 * hi + r) * DD + col] = f2bf(v[r] + bv);
                } else if (col < 256) {
                    int head = col >> 5, dh = col & 31;
                    #pragma unroll
                    for (int r = 0; r < 4; r++) {
                        int n = (rw0 + 4 * hi + r) & (NN - 1);
                        O0[(((size_t)(bb * HH + head) * NN + n) << 5) + dh] = f2bf(v[r]);
                    }
                } else if (col < 512) {
                    int cc = col - 256;
                    int bhv = bb * HH + (cc >> 5);
                    int dh = cc & 31;
                    int n0 = (rw0 + 4 * hi) & (NN - 1);
                    int m = n0 >> 2;
                    int p_ = m >> 3, s_ = (m >> 2) & 1, g_ = m & 3;
                    int n0p = (8 * p_ + 2 * g_ + s_) << 2;
                    ushort4 uv = {f2bf(v[0]), f2bf(v[1]), f2bf(v[2]), f2bf(v[3])};
                    *(ushort4*)(O1 + ((size_t)bhv * DH + dh) * NN + n0p) = uv;
                } else {
                    #pragma unroll
                    for (int r = 0; r < 4; r++)
                        O2[(size_t)(rw0 + 4 * hi + r) * 256 + (col - 512)] = f2bf(v[r]);
                }
            } else {
                #pragma unroll
                for (int r = 0; r < 4; r++)
                    O0[(size_t)(rw0 + 4 * hi + r) * DD + col] = f2bf(v[r]);
            }
        }
    }
}

// ---------------------------------------------------------------------------
// K3: LDS-staged swapped-operand attention (verified r8-r11).
__global__ __launch_bounds__(256) void attn8_k(
    const ushort* __restrict__ gq, const ushort* __restrict__ gkT,
    const ushort* __restrict__ vTp, const uint* __restrict__ mbt,
    ushort* __restrict__ headsB) {
    int j = blockIdx.x;
    int bh = j & 255, half = j >> 8;
    int b = bh >> 3, h = bh & 7;
    int tid = threadIdx.x;
    int w = tid >> 6, l = tid & 63;
    int lo = l & 15, hi = l >> 4;

    __shared__ ushort Ks[16384];
    __shared__ ushort Vs[16384];
    __shared__ ushort OT[4][16][40];

    {
        const uint4* src = (const uint4*)(gkT + (size_t)bh * (NN * DH));
        #pragma unroll
        for (int i = 0; i < 8; i++) {
            int u = i * 256 + tid;
            uint4 v = src[u];
            int G = u << 4;
            int a = G ^ (((G >> 6) & 7) << 4);
            *(uint4*)((char*)Ks + a) = v;
        }
    }
    {
        const uint4* src = (const uint4*)(vTp + (size_t)bh * (DH * NN));
        #pragma unroll
        for (int i = 0; i < 8; i++) {
            int u = i * 256 + tid;
            uint4 v = src[u];
            int G = u << 4;
            int a = G ^ (((G >> 10) & 7) << 4);
            *(uint4*)((char*)Vs + a) = v;
        }
    }
    __syncthreads();

    const f32x4 zero = {0.f, 0.f, 0.f, 0.f};
    const bf16x8 ones = {(short)0x3F80, (short)0x3F80, (short)0x3F80,
                         (short)0x3F80, (short)0x3F80, (short)0x3F80,
                         (short)0x3F80, (short)0x3F80};
    const float sc = 0.17677669529663687f;  // 1/sqrt(32)
    int q0 = half * 256;
    int kswz = (lo & 7) << 4;

    for (int qc2 = 0; qc2 < 4; qc2++) {
        int t0 = q0 + qc2 * 64 + w * 16;
        bf16x8 qf = *(const bf16x8*)(gq + ((size_t)(b * TT + t0 + lo)) * DD + h * DH + hi * 8);
        uint4 mq = *(const uint4*)(mbt + ((size_t)(b * TT + t0 + lo)) * 16 + 4 * hi);

        f32x4 o0 = zero, o1 = zero, osum = zero;

        #pragma unroll
        for (int p = 0; p < 16; p++) {
            int n0 = 32 * p + lo;
            bf16x8 kf0 = *(const bf16x8*)((char*)Ks + ((n0 * 64 + hi * 16) ^ kswz));
            bf16x8 kf1 = *(const bf16x8*)((char*)Ks + (((n0 + 16) * 64 + hi * 16) ^ kswz));
            f32x4 s0 = __builtin_amdgcn_mfma_f32_16x16x32_bf16(kf0, qf, zero, 0, 0, 0);
            f32x4 s1 = __builtin_amdgcn_mfma_f32_16x16x32_bf16(kf1, qf, zero, 0, 0, 0);
            union { bf16x8 v; uint u[4]; } pf;
            {
                const int c = 2 * p;
                float e0 = ((mq.x >> c) & 1u) ? __expf(s0[0] * sc) : 0.f;
                float e1 = ((mq.y >> c) & 1u) ? __expf(s0[1] * sc) : 0.f;
                float e2 = ((mq.z >> c) & 1u) ? __expf(s0[2] * sc) : 0.f;
                float e3 = ((mq.w >> c) & 1u) ? __expf(s0[3] * sc) : 0.f;
                pf.u[0] = pk2t(e0, e1);
                pf.u[1] = pk2t(e2, e3);
            }
            {
                const int c = 2 * p + 1;
                float e0 = ((mq.x >> c) & 1u) ? __expf(s1[0] * sc) : 0.f;
                float e1 = ((mq.y >> c) & 1u) ? __expf(s1[1] * sc) : 0.f;
                float e2 = ((mq.z >> c) & 1u) ? __expf(s1[2] * sc) : 0.f;
                float e3 = ((mq.w >> c) & 1u) ? __expf(s1[3] * sc) : 0.f;
                pf.u[2] = pk2t(e0, e1);
                pf.u[3] = pk2t(e2, e3);
            }
            int vo = (32 * p + 8 * hi) * 2;
            bf16x8 va0 = *(const bf16x8*)((char*)Vs + (((lo << 10) + vo) ^ kswz));
            bf16x8 va1 = *(const bf16x8*)((char*)Vs + ((((lo + 16) << 10) + vo) ^ kswz));
            o0 = __builtin_amdgcn_mfma_f32_16x16x32_bf16(va0, pf.v, o0, 0, 0, 0);
            o1 = __builtin_amdgcn_mfma_f32_16x16x32_bf16(va1, pf.v, o1, 0, 0, 0);
            osum = __builtin_amdgcn_mfma_f32_16x16x32_bf16(ones, pf.v, osum, 0, 0, 0);
        }

        float inv = 1.0f / fmaxf(osum[0], 1e-30f);

        #pragma unroll
        for (int r = 0; r < 4; r++) {
            OT[w][lo][4 * hi + r] = tr16(o0[r] * inv);
            OT[w][lo][16 + 4 * hi + r] = tr16(o1[r] * inv);
        }
        bf16x8 ov = *(const bf16x8*)(&OT[w][lo][hi * 8]);
        *(bf16x8*)(headsB + ((size_t)(b * TT + t0 + lo)) * DD + h * DH + hi * 8) = ov;
    }
}

// ---------------------------------------------------------------------------
// K5a: pointer-logits GEMM (gemm3 shape, per batch) -> bf16 logits + per-
// (row, col-panel) masked exp-sum partials (deterministic, no atomics).
__global__ __launch_bounds__(256) void logits_mm_k(
    const ushort* __restrict__ glimpse, const ushort* __restrict__ lkb,
    const uint* __restrict__ mbt, ushort* __restrict__ logitsB,
    float* __restrict__ psum) {
    int j = blockIdx.x;  // 32 b x 4 bx x 8 by
    int b = j >> 5;
    int bx = (j >> 3) & 3, by = j & 7;
    int row0 = bx * 128, col0 = by * 64;
    int tid = threadIdx.x;
    int w = tid >> 6, l = tid & 63;
    int lo = l & 15, hi = l >> 4;

    __shared__ ushort As[128 * 64];
    __shared__ ushort Bs[64 * 64];

    const ushort* Abase = glimpse + (size_t)b * TT * DD;
    const ushort* Bbase = lkb + (size_t)b * NN * DD;

    const f32x4 zero = {0.f, 0.f, 0.f, 0.f};
    f32x4 acc[2][4] = {{zero, zero, zero, zero}, {zero, zero, zero, zero}};

    for (int kk = 0; kk < 4; kk++) {
        if (kk) __syncthreads();
        #pragma unroll
        for (int i = 0; i < 4; i++) {
            int u = i * 256 + tid;
            int row = u >> 3, slot = u & 7;
            uint4 v = *(const uint4*)(Abase + (size_t)(row0 + row) * DD + kk * 64 + slot * 8);
            *(uint4*)((char*)As + row * 128 + ((slot ^ (row & 7)) << 4)) = v;
        }
        #pragma unroll
        for (int i = 0; i < 2; i++) {
            int u = i * 256 + tid;
            int row = u >> 3, slot = u & 7;
            uint4 v = *(const uint4*)(Bbase + (size_t)(col0 + row) * DD + kk * 64 + slot * 8);
            *(uint4*)((char*)Bs + row * 128 + ((slot ^ (row & 7)) << 4)) = v;
        }
        __syncthreads();
        #pragma unroll
        for (int ks = 0; ks < 2; ks++) {
            int sx = ((ks * 4 + hi) ^ (lo & 7)) << 4;
            bf16x8 af0 = *(const bf16x8*)((char*)As + (w * 32 + lo) * 128 + sx);
            bf16x8 af1 = *(const bf16x8*)((char*)As + (w * 32 + 16 + lo) * 128 + sx);
            #pragma unroll
            for (int c = 0; c < 4; c++) {
                bf16x8 bf = *(const bf16x8*)((char*)Bs + (c * 16 + lo) * 128 + sx);
                acc[0][c] = __builtin_amdgcn_mfma_f32_16x16x32_bf16(af0, bf, acc[0][c], 0, 0, 0);
                acc[1][c] = __builtin_amdgcn_mfma_f32_16x16x32_bf16(af1, bf, acc[1][c], 0, 0, 0);
            }
        }
    }

    #pragma unroll
    for (int rg = 0; rg < 2; rg++) {
        int rw = row0 + w * 32 + rg * 16;  // + 4hi + r
        uint mw[4];
        #pragma unroll
        for (int r = 0; r < 4; r++)
            mw[r] = mbt[((size_t)(b * TT + rw + 4 * hi + r)) * 16 + lo];
        float rsum[4] = {0.f, 0.f, 0.f, 0.f};
        #pragma unroll
        for (int c = 0; c < 4; c++) {
            int col = col0 + c * 16 + lo;
            int cg = by * 4 + c;  // mask bit index for this 16-col chunk
            #pragma unroll
            for (int r = 0; r < 4; r++) {
                float t = fast_tanh10(acc[rg][c][r] * 0.0625f);
                logitsB[((size_t)(b * TT + rw + 4 * hi + r)) * NN + col] = tr16(t);
                rsum[r] += ((mw[r] >> cg) & 1u) ? __expf(t - 10.f) : 0.f;
            }
        }
        #pragma unroll
        for (int r = 0; r < 4; r++) {
            #pragma unroll
            for (int o = 1; o < 16; o <<= 1) rsum[r] += __shfl_xor(rsum[r], o);
        }
        if (lo == 0) {
            #pragma unroll
            for (int r = 0; r < 4; r++)
                psum[((size_t)(b * TT + rw + 4 * hi + r)) * 8 + by] = rsum[r];
        }
    }
}

// K5b: out = (mask ? logit : NEG_INF) - lse, lse = 10 + log(sum8 psum).
// Block = 8 rows; fully coalesced. grid 2048.
__global__ __launch_bounds__(256) void logits_fin_k(
    const ushort* __restrict__ logitsB, const float* __restrict__ psum,
    const uint* __restrict__ mbt, float* __restrict__ out) {
    int r0 = blockIdx.x * 8;
    int tid = threadIdx.x;
    __shared__ float lsev[8];
    __shared__ uint mwv[8][16];
    if (tid < 128) {
        mwv[tid >> 4][tid & 15] = mbt[(size_t)(r0 + (tid >> 4)) * 16 + (tid & 15)];
    } else if (tid < 136) {
        int rr = tid - 128;
        const float* pp = psum + (size_t)(r0 + rr) * 8;
        float s = 0.f;
        #pragma unroll
        for (int p = 0; p < 8; p++) s += pp[p];
        lsev[rr] = 10.f + __logf(fmaxf(s, 1e-37f));
    }
    __syncthreads();
    int row = tid >> 5, n0 = (tid & 31) * 16;
    float lse = lsev[row];
    const ushort* lb = logitsB + (size_t)(r0 + row) * NN + n0;
    bf16x8 v0 = *(const bf16x8*)(lb);
    bf16x8 v1 = *(const bf16x8*)(lb + 8);
    float ov[16];
    #pragma unroll
    for (int jj = 0; jj < 16; jj++) {
        int n = n0 + jj;
        uint bit = (mwv[row][n & 15] >> (n >> 4)) & 1u;
        float lv = bf2f((ushort)(jj < 8 ? v0[jj] : v1[jj - 8]));
        ov[jj] = bit ? lv - lse : NEG_INF - lse;
    }
    float* ob = out + (size_t)(r0 + row) * NN + n0;
    #pragma unroll
    for (int q = 0; q < 4; q++)
        *(float4*)(ob + q * 4) = *(float4*)(&ov[q * 4]);
}

// ---------------------------------------------------------------------------
extern "C" void kernel_launch(void* const* d_in, const int* in_sizes, int n_in,
                              void* d_out, int out_size, void* d_ws,
                              size_t ws_size, hipStream_t stream) {
    const float* emb = (const float*)d_in[0];
    const int* cur   = (const int*)d_in[1];
    const int* mask  = (const int*)d_in[2];
    const float* Wn  = (const float*)d_in[3];
    const float* Wf  = (const float*)d_in[4];
    const float* Ws  = (const float*)d_in[5];
    const float* Wo  = (const float*)d_in[6];
    float* out = (float*)d_out;

    const size_t SLABE = (size_t)BB * NN * DD;
    ushort* embB     = (ushort*)d_ws;
    ushort* gkT      = embB + SLABE;     // [bh][n][32]
    ushort* vTp      = gkT + SLABE;      // [bh][dh][n''] pre-permuted
    ushort* lkb      = vTp + SLABE;      // [b*N+n][256]
    ushort* gq       = lkb + SLABE;      // [b*T+t][256]
    ushort* headsB   = gq + SLABE;
    ushort* glimpseB = headsB + SLABE;
    ushort* WnT      = glimpseB + SLABE;
    ushort* WsT      = WnT + 768 * 256;
    ushort* WoT      = WsT + 256 * 256;
    uint*   mbt      = (uint*)(WoT + 256 * 256);
    float*  ctx      = (float*)(mbt + (size_t)BB * TT * 16);
    float*  partial  = ctx + (size_t)BB * DD;
    // K5 scratch reuses embB/gkT/vTp region (dead after attn8):
    ushort* logitsB  = embB;                       // 16.8 MB
    float*  psum     = (float*)(embB + (size_t)BB * TT * NN);  // 512 KB

    prep_all_k<<<1600, 256, 0, stream>>>(emb, embB, partial, Wn, Ws, Wo,
                                         WnT, WsT, WoT, mask, mbt);
    ctx_mm_k<<<BB, 256, 0, stream>>>(partial, Wf, ctx);
    // K1 (1536 blocks) + K2 (512 blocks) fused
    gemm3_k<0><<<2048, 256, 0, stream>>>(embB, WnT, WsT, gkT, vTp, lkb, gq,
                                         ctx, cur);
    attn8_k<<<512, 256, 0, stream>>>(gq, gkT, vTp, mbt, headsB);
    // K4
    gemm3_k<1><<<512, 256, 0, stream>>>(headsB, WoT, nullptr, glimpseB,
                                        nullptr, nullptr, nullptr, nullptr,
                                        nullptr);
    // K5: two-pass pointer logits + log_softmax
    logits_mm_k<<<1024, 256, 0, stream>>>(glimpseB, lkb, mbt, logitsB, psum);
    logits_fin_k<<<BB * TT / 8, 256, 0, stream>>>(logitsB, psum, mbt, out);
}

// Round 13
// 119.396 us; speedup vs baseline: 1.1421x; 1.0610x over previous
//
#include <hip/hip_runtime.h>
#include <hip/hip_bf16.h>

constexpr int BB = 32;    // batch
constexpr int TT = 512;   // decode steps
constexpr int NN = 512;   // nodes
constexpr int DD = 256;   // model dim
constexpr int HH = 8;     // heads
constexpr int DH = 32;    // head dim
#define NEG_INF (-1e9f)

typedef __attribute__((ext_vector_type(8))) short bf16x8;
typedef __attribute__((ext_vector_type(4))) float f32x4;

__device__ inline ushort f2bf(float x) {
    union { float f; unsigned u; } c; c.f = x;
    unsigned u = c.u + 0x7fffu + ((c.u >> 16) & 1u);  // RNE
    return (ushort)(u >> 16);
}
__device__ inline uint pk2t(float a, float b) {  // truncating pack
    return __builtin_amdgcn_perm(__float_as_uint(b), __float_as_uint(a),
                                 0x07060302u);
}
__device__ inline ushort tr16(float x) { return (ushort)(__float_as_uint(x) >> 16); }
__device__ inline float bf2f(ushort u) {
    union { uint u; float f; } c; c.u = (uint)u << 16; return c.f;
}
__device__ inline float fast_tanh10(float x) {
    x = fminf(fmaxf(x, -20.f), 20.f);
    float e2 = __expf(2.f * x);
    return 10.f * (1.f - 2.f / (e2 + 1.f));
}

// ---------------------------------------------------------------------------
// prep_all: [0,256) emb cvt+partials | [256,576) weight transposes |
//           [576,1600) mask bit-pack
__global__ __launch_bounds__(256) void prep_all_k(
    const float* __restrict__ emb, ushort* __restrict__ embB,
    float* __restrict__ partial, const float* __restrict__ Wn,
    const float* __restrict__ Ws, const float* __restrict__ Wo,
    ushort* __restrict__ WnT, ushort* __restrict__ WsT,
    ushort* __restrict__ WoT, const int* __restrict__ mask,
    uint* __restrict__ mbt) {
    int j = blockIdx.x;
    int tid = threadIdx.x;
    if (j < 256) {
        int b = j >> 3, part = j & 7, d = tid;
        const float* eb = emb + ((size_t)b * NN + part * 64) * DD + d;
        ushort* ob = embB + ((size_t)b * NN + part * 64) * DD + d;
        float s = 0.f;
        #pragma unroll 4
        for (int i = 0; i < 64; i++) {
            float v = eb[(size_t)i * DD];
            s += v;
            ob[(size_t)i * DD] = f2bf(v);
        }
        partial[((size_t)b * 8 + part) * DD + d] = s;
    } else if (j < 576) {
        __shared__ float t[32][33];
        int g = j - 256;
        int gx = g % 40, gy = g / 40;
        const float* W;
        ushort* WT;
        int NC, xb;
        if (gx < 24)      { W = Wn; WT = WnT; NC = 768; xb = gx; }
        else if (gx < 32) { W = Ws; WT = WsT; NC = 256; xb = gx - 24; }
        else              { W = Wo; WT = WoT; NC = 256; xb = gx - 32; }
        int tx = tid & 31, ty = tid >> 5;
        int x = xb * 32 + tx;
        int y0 = gy * 32;
        #pragma unroll
        for (int i = 0; i < 4; i++)
            t[ty + i * 8][tx] = W[(size_t)(y0 + ty + i * 8) * NC + x];
        __syncthreads();
        #pragma unroll
        for (int i = 0; i < 4; i++)
            WT[(size_t)(xb * 32 + ty + i * 8) * 256 + y0 + tx] =
                f2bf(t[tx][ty + i * 8]);
    } else {
        int idx = (j - 576) * 256 + tid;
        int row = idx >> 4, w = idx & 15;
        const int* mr = mask + (size_t)row * NN + w;
        uint u = 0;
        #pragma unroll
        for (int c = 0; c < 32; c++) u |= (uint)(mr[c * 16] != 0) << c;
        mbt[idx] = u;
    }
}

// ---------------------------------------------------------------------------
// gemm3: BM=128 x BN=64 x BK=64, 24KB LDS, 4 k-iters (verified r11/r12).
// Grid is BY-INNER (same-A blocks consecutive -> same XCD -> A L2-resident).
// TASK 0: j<1536 -> K1 (proj -> gkT/vTp/lk, bx=j/12, by=j%12);
//         j>=1536 -> K2 (gq = emb[cur]@Ws + ctx, ctx computed IN-BLOCK).
// TASK 1: K4 (glimpse = heads @ Wo), bx=j>>2, by=j&3.
template <int TASK>
__global__ __launch_bounds__(256) void gemm3_k(
    const ushort* __restrict__ A0, const ushort* __restrict__ WT0,
    const ushort* __restrict__ WT1, ushort* __restrict__ O0,
    ushort* __restrict__ O1, ushort* __restrict__ O2,
    ushort* __restrict__ O3, const float* __restrict__ partial,
    const float* __restrict__ Wf, const int* __restrict__ cur) {
    int j = blockIdx.x;
    bool k2 = (TASK == 0) && (j >= 1536);
    int bx, by;
    if (TASK == 0) {
        if (k2) { int jj = j - 1536; bx = jj >> 2; by = jj & 3; }
        else    { bx = j / 12; by = j - bx * 12; }
    } else {
        bx = j >> 2; by = j & 3;
    }
    int row0 = bx * 128, col0 = by * 64;
    int tid = threadIdx.x;
    int w = tid >> 6, l = tid & 63;
    int lo = l & 15, hi = l >> 4;

    __shared__ ushort As[128 * 64];  // 16KB
    __shared__ ushort Bs[64 * 64];   // 8KB
    __shared__ float ctxs[64];

    const ushort* WT = k2 ? WT1 : WT0;
    const f32x4 zero = {0.f, 0.f, 0.f, 0.f};
    f32x4 acc[2][4] = {{zero, zero, zero, zero}, {zero, zero, zero, zero}};

    for (int kk = 0; kk < 4; kk++) {
        if (kk) __syncthreads();
        #pragma unroll
        for (int i = 0; i < 4; i++) {
            int u = i * 256 + tid;
            int row = u >> 3, slot = u & 7;
            int arow = row0 + row;
            const ushort* ap;
            if (k2) {
                int b = arow >> 9;
                ap = A0 + ((size_t)(b * NN + cur[arow])) * DD;
            } else {
                ap = A0 + (size_t)arow * DD;
            }
            uint4 v = *(const uint4*)(ap + kk * 64 + slot * 8);
            *(uint4*)((char*)As + row * 128 + ((slot ^ (row & 7)) << 4)) = v;
        }
        #pragma unroll
        for (int i = 0; i < 2; i++) {
            int u = i * 256 + tid;
            int row = u >> 3, slot = u & 7;
            uint4 v = *(const uint4*)(WT + (size_t)(col0 + row) * 256 + kk * 64 + slot * 8);
            *(uint4*)((char*)Bs + row * 128 + ((slot ^ (row & 7)) << 4)) = v;
        }
        __syncthreads();
        #pragma unroll
        for (int ks = 0; ks < 2; ks++) {
            int sx = ((ks * 4 + hi) ^ (lo & 7)) << 4;
            bf16x8 af0 = *(const bf16x8*)((char*)As + (w * 32 + lo) * 128 + sx);
            bf16x8 af1 = *(const bf16x8*)((char*)As + (w * 32 + 16 + lo) * 128 + sx);
            #pragma unroll
            for (int c = 0; c < 4; c++) {
                bf16x8 bf = *(const bf16x8*)((char*)Bs + (c * 16 + lo) * 128 + sx);
                acc[0][c] = __builtin_amdgcn_mfma_f32_16x16x32_bf16(af0, bf, acc[0][c], 0, 0, 0);
                acc[1][c] = __builtin_amdgcn_mfma_f32_16x16x32_bf16(af1, bf, acc[1][c], 0, 0, 0);
            }
        }
    }

    int bbq = row0 >> 9;  // batch (row panels never cross batches)
    if (k2) {
        // in-block ctx: ctx[col] = (sum_p partial[b][p][:]/512) @ Wf[:, col]
        __syncthreads();  // As free
        float* fs = (float*)As;  // mean[256] then partial reduce [4][64]
        float mk = 0.f;
        #pragma unroll
        for (int p = 0; p < 8; p++)
            mk += partial[(size_t)bbq * 2048 + p * 256 + tid];
        fs[tid] = mk * (1.0f / 512.0f);
        __syncthreads();
        int cc = tid & 63, part = tid >> 6;
        float cs = 0.f;
        #pragma unroll 16
        for (int k = part * 64; k < part * 64 + 64; k++)
            cs += fs[k] * Wf[(size_t)k * 256 + col0 + cc];
        float* fs2 = fs + 256;
        fs2[part * 64 + cc] = cs;
        __syncthreads();
        if (tid < 64)
            ctxs[tid] = fs2[tid] + fs2[64 + tid] + fs2[128 + tid] + fs2[192 + tid];
        __syncthreads();
    }

    #pragma unroll
    for (int rg = 0; rg < 2; rg++) {
        int rw0 = row0 + w * 32 + rg * 16;
        int bb = rw0 >> 9;
        #pragma unroll
        for (int c = 0; c < 4; c++) {
            int col = col0 + c * 16 + lo;
            float v[4];
            #pragma unroll
            for (int r = 0; r < 4; r++) v[r] = acc[rg][c][r];
            if constexpr (TASK == 0) {
                if (k2) {
                    float bv = ctxs[col - col0];
                    #pragma unroll
                    for (int r = 0; r < 4; r++)
                        O3[(size_t)(rw0 + 4 * hi + r) * DD + col] = f2bf(v[r] + bv);
                } else if (col < 256) {
                    int head = col >> 5, dh = col & 31;
                    #pragma unroll
                    for (int r = 0; r < 4; r++) {
                        int n = (rw0 + 4 * hi + r) & (NN - 1);
                        O0[(((size_t)(bb * HH + head) * NN + n) << 5) + dh] = f2bf(v[r]);
                    }
                } else if (col < 512) {
                    int cc2 = col - 256;
                    int bhv = bb * HH + (cc2 >> 5);
                    int dh = cc2 & 31;
                    int n0 = (rw0 + 4 * hi) & (NN - 1);
                    int m = n0 >> 2;
                    int p_ = m >> 3, s_ = (m >> 2) & 1, g_ = m & 3;
                    int n0p = (8 * p_ + 2 * g_ + s_) << 2;
                    ushort4 uv = {f2bf(v[0]), f2bf(v[1]), f2bf(v[2]), f2bf(v[3])};
                    *(ushort4*)(O1 + ((size_t)bhv * DH + dh) * NN + n0p) = uv;
                } else {
                    #pragma unroll
                    for (int r = 0; r < 4; r++)
                        O2[(size_t)(rw0 + 4 * hi + r) * 256 + (col - 512)] = f2bf(v[r]);
                }
            } else {
                #pragma unroll
                for (int r = 0; r < 4; r++)
                    O0[(size_t)(rw0 + 4 * hi + r) * DD + col] = f2bf(v[r]);
            }
        }
    }
}

// ---------------------------------------------------------------------------
// K3: two-phase LDS-staged swapped-operand attention. Phase = 256 keys
// (16KB K + 16KB V staged at a time; 37KB LDS -> 3 blocks/CU at <=168 VGPR).
// No-max softmax (verified r5-r12) => key-split needs no rescaling: O and
// sum accumulate across phases directly. o-state for 4 q-chunks persists.
__global__ __launch_bounds__(256, 3) void attn9_k(
    const ushort* __restrict__ gq, const ushort* __restrict__ gkT,
    const ushort* __restrict__ vTp, const uint* __restrict__ mbt,
    ushort* __restrict__ headsB) {
    int j = blockIdx.x;
    int bh = j & 255, half = j >> 8;
    int b = bh >> 3, h = bh & 7;
    int tid = threadIdx.x;
    int w = tid >> 6, l = tid & 63;
    int lo = l & 15, hi = l >> 4;

    __shared__ ushort Ks[8192];       // 16KB: 256 n-rows x 64B, ^((n&7)<<4)
    __shared__ ushort Vs[8192];       // 16KB: 32 dh-rows x 512B, ^((dh&7)<<4)
    __shared__ ushort OT[4][16][40];  // 5KB transpose staging

    const f32x4 zero = {0.f, 0.f, 0.f, 0.f};
    const bf16x8 ones = {(short)0x3F80, (short)0x3F80, (short)0x3F80,
                         (short)0x3F80, (short)0x3F80, (short)0x3F80,
                         (short)0x3F80, (short)0x3F80};
    const float sc = 0.17677669529663687f;  // 1/sqrt(32)
    int q0 = half * 256;
    int kswz = (lo & 7) << 4;

    f32x4 o0[4] = {zero, zero, zero, zero};
    f32x4 o1[4] = {zero, zero, zero, zero};
    f32x4 osum[4] = {zero, zero, zero, zero};

    const char* kbase = (const char*)(gkT + (size_t)bh * (NN * DH));
    const char* vbase = (const char*)(vTp + (size_t)bh * (DH * NN));

    for (int ph = 0; ph < 2; ph++) {
        if (ph) __syncthreads();
        // stage K half (16KB): rows nn (64B)
        {
            const char* ksrc = kbase + ph * 16384;
            #pragma unroll
            for (int i = 0; i < 4; i++) {
                int u = i * 256 + tid;
                int nn = u >> 2, slot = u & 3;
                uint4 v = *(const uint4*)(ksrc + nn * 64 + slot * 16);
                *(uint4*)((char*)Ks + ((nn * 64 + slot * 16) ^ ((nn & 7) << 4))) = v;
            }
        }
        // stage V half (16KB): rows dh (512B halves of 1KB rows)
        {
            const char* vsrc = vbase + ph * 512;
            #pragma unroll
            for (int i = 0; i < 4; i++) {
                int u = i * 256 + tid;
                int dh = u >> 5, slot = u & 31;
                uint4 v = *(const uint4*)(vsrc + dh * 1024 + slot * 16);
                *(uint4*)((char*)Vs + ((dh * 512 + slot * 16) ^ ((dh & 7) << 4))) = v;
            }
        }
        __syncthreads();

        #pragma unroll
        for (int qc2 = 0; qc2 < 4; qc2++) {
            int t0 = q0 + qc2 * 64 + w * 16;
            bf16x8 qf = *(const bf16x8*)(gq + ((size_t)(b * TT + t0 + lo)) * DD + h * DH + hi * 8);
            uint4 mq = *(const uint4*)(mbt + ((size_t)(b * TT + t0 + lo)) * 16 + 4 * hi);

            #pragma unroll 4
            for (int p = 0; p < 8; p++) {
                int nn = 32 * p + lo;
                bf16x8 kf0 = *(const bf16x8*)((char*)Ks + ((nn * 64 + hi * 16) ^ kswz));
                bf16x8 kf1 = *(const bf16x8*)((char*)Ks + (((nn + 16) * 64 + hi * 16) ^ kswz));
                f32x4 s0 = __builtin_amdgcn_mfma_f32_16x16x32_bf16(kf0, qf, zero, 0, 0, 0);
                f32x4 s1 = __builtin_amdgcn_mfma_f32_16x16x32_bf16(kf1, qf, zero, 0, 0, 0);
                union { bf16x8 v; uint u[4]; } pf;
                {
                    int c = ph * 16 + 2 * p;
                    float e0 = ((mq.x >> c) & 1u) ? __expf(s0[0] * sc) : 0.f;
                    float e1 = ((mq.y >> c) & 1u) ? __expf(s0[1] * sc) : 0.f;
                    float e2 = ((mq.z >> c) & 1u) ? __expf(s0[2] * sc) : 0.f;
                    float e3 = ((mq.w >> c) & 1u) ? __expf(s0[3] * sc) : 0.f;
                    pf.u[0] = pk2t(e0, e1);
                    pf.u[1] = pk2t(e2, e3);
                }
                {
                    int c = ph * 16 + 2 * p + 1;
                    float e0 = ((mq.x >> c) & 1u) ? __expf(s1[0] * sc) : 0.f;
                    float e1 = ((mq.y >> c) & 1u) ? __expf(s1[1] * sc) : 0.f;
                    float e2 = ((mq.z >> c) & 1u) ? __expf(s1[2] * sc) : 0.f;
                    float e3 = ((mq.w >> c) & 1u) ? __expf(s1[3] * sc) : 0.f;
                    pf.u[2] = pk2t(e0, e1);
                    pf.u[3] = pk2t(e2, e3);
                }
                int vo = (32 * p + 8 * hi) * 2;
                bf16x8 va0 = *(const bf16x8*)((char*)Vs + ((lo * 512 + vo) ^ kswz));
                bf16x8 va1 = *(const bf16x8*)((char*)Vs + (((lo + 16) * 512 + vo) ^ kswz));
                o0[qc2] = __builtin_amdgcn_mfma_f32_16x16x32_bf16(va0, pf.v, o0[qc2], 0, 0, 0);
                o1[qc2] = __builtin_amdgcn_mfma_f32_16x16x32_bf16(va1, pf.v, o1[qc2], 0, 0, 0);
                osum[qc2] = __builtin_amdgcn_mfma_f32_16x16x32_bf16(ones, pf.v, osum[qc2], 0, 0, 0);
            }
        }
    }

    #pragma unroll
    for (int qc2 = 0; qc2 < 4; qc2++) {
        int t0 = q0 + qc2 * 64 + w * 16;
        float inv = 1.0f / fmaxf(osum[qc2][0], 1e-30f);
        #pragma unroll
        for (int r = 0; r < 4; r++) {
            OT[w][lo][4 * hi + r] = tr16(o0[qc2][r] * inv);
            OT[w][lo][16 + 4 * hi + r] = tr16(o1[qc2][r] * inv);
        }
        bf16x8 ov = *(const bf16x8*)(&OT[w][lo][hi * 8]);
        *(bf16x8*)(headsB + ((size_t)(b * TT + t0 + lo)) * DD + h * DH + hi * 8) = ov;
    }
}

// ---------------------------------------------------------------------------
// K5a: pointer-logits GEMM -> bf16 logits + per-(row, col-panel) masked
// exp-sum partials (deterministic, no atomics). (verified r12)
__global__ __launch_bounds__(256) void logits_mm_k(
    const ushort* __restrict__ glimpse, const ushort* __restrict__ lkb,
    const uint* __restrict__ mbt, ushort* __restrict__ logitsB,
    float* __restrict__ psum) {
    int j = blockIdx.x;  // 32 b x 4 bx x 8 by
    int b = j >> 5;
    int bx = (j >> 3) & 3, by = j & 7;
    int row0 = bx * 128, col0 = by * 64;
    int tid = threadIdx.x;
    int w = tid >> 6, l = tid & 63;
    int lo = l & 15, hi = l >> 4;

    __shared__ ushort As[128 * 64];
    __shared__ ushort Bs[64 * 64];

    const ushort* Abase = glimpse + (size_t)b * TT * DD;
    const ushort* Bbase = lkb + (size_t)b * NN * DD;

    const f32x4 zero = {0.f, 0.f, 0.f, 0.f};
    f32x4 acc[2][4] = {{zero, zero, zero, zero}, {zero, zero, zero, zero}};

    for (int kk = 0; kk < 4; kk++) {
        if (kk) __syncthreads();
        #pragma unroll
        for (int i = 0; i < 4; i++) {
            int u = i * 256 + tid;
            int row = u >> 3, slot = u & 7;
            uint4 v = *(const uint4*)(Abase + (size_t)(row0 + row) * DD + kk * 64 + slot * 8);
            *(uint4*)((char*)As + row * 128 + ((slot ^ (row & 7)) << 4)) = v;
        }
        #pragma unroll
        for (int i = 0; i < 2; i++) {
            int u = i * 256 + tid;
            int row = u >> 3, slot = u & 7;
            uint4 v = *(const uint4*)(Bbase + (size_t)(col0 + row) * DD + kk * 64 + slot * 8);
            *(uint4*)((char*)Bs + row * 128 + ((slot ^ (row & 7)) << 4)) = v;
        }
        __syncthreads();
        #pragma unroll
        for (int ks = 0; ks < 2; ks++) {
            int sx = ((ks * 4 + hi) ^ (lo & 7)) << 4;
            bf16x8 af0 = *(const bf16x8*)((char*)As + (w * 32 + lo) * 128 + sx);
            bf16x8 af1 = *(const bf16x8*)((char*)As + (w * 32 + 16 + lo) * 128 + sx);
            #pragma unroll
            for (int c = 0; c < 4; c++) {
                bf16x8 bf = *(const bf16x8*)((char*)Bs + (c * 16 + lo) * 128 + sx);
                acc[0][c] = __builtin_amdgcn_mfma_f32_16x16x32_bf16(af0, bf, acc[0][c], 0, 0, 0);
                acc[1][c] = __builtin_amdgcn_mfma_f32_16x16x32_bf16(af1, bf, acc[1][c], 0, 0, 0);
            }
        }
    }

    #pragma unroll
    for (int rg = 0; rg < 2; rg++) {
        int rw = row0 + w * 32 + rg * 16;
        uint mw[4];
        #pragma unroll
        for (int r = 0; r < 4; r++)
            mw[r] = mbt[((size_t)(b * TT + rw + 4 * hi + r)) * 16 + lo];
        float rsum[4] = {0.f, 0.f, 0.f, 0.f};
        #pragma unroll
        for (int c = 0; c < 4; c++) {
            int col = col0 + c * 16 + lo;
            int cg = by * 4 + c;
            #pragma unroll
            for (int r = 0; r < 4; r++) {
                float t = fast_tanh10(acc[rg][c][r] * 0.0625f);
                logitsB[((size_t)(b * TT + rw + 4 * hi + r)) * NN + col] = tr16(t);
                rsum[r] += ((mw[r] >> cg) & 1u) ? __expf(t - 10.f) : 0.f;
            }
        }
        #pragma unroll
        for (int r = 0; r < 4; r++) {
            #pragma unroll
            for (int o = 1; o < 16; o <<= 1) rsum[r] += __shfl_xor(rsum[r], o);
        }
        if (lo == 0) {
            #pragma unroll
            for (int r = 0; r < 4; r++)
                psum[((size_t)(b * TT + rw + 4 * hi + r)) * 8 + by] = rsum[r];
        }
    }
}

// K5b: out = (mask ? logit : NEG_INF) - lse, lse = 10 + log(sum8 psum).
__global__ __launch_bounds__(256) void logits_fin_k(
    const ushort* __restrict__ logitsB, const float* __restrict__ psum,
    const uint* __restrict__ mbt, float* __restrict__ out) {
    int r0 = blockIdx.x * 8;
    int tid = threadIdx.x;
    __shared__ float lsev[8];
    __shared__ uint mwv[8][16];
    if (tid < 128) {
        mwv[tid >> 4][tid & 15] = mbt[(size_t)(r0 + (tid >> 4)) * 16 + (tid & 15)];
    } else if (tid < 136) {
        int rr = tid - 128;
        const float* pp = psum + (size_t)(r0 + rr) * 8;
        float s = 0.f;
        #pragma unroll
        for (int p = 0; p < 8; p++) s += pp[p];
        lsev[rr] = 10.f + __logf(fmaxf(s, 1e-37f));
    }
    __syncthreads();
    int row = tid >> 5, n0 = (tid & 31) * 16;
    float lse = lsev[row];
    const ushort* lb = logitsB + (size_t)(r0 + row) * NN + n0;
    bf16x8 v0 = *(const bf16x8*)(lb);
    bf16x8 v1 = *(const bf16x8*)(lb + 8);
    float ov[16];
    #pragma unroll
    for (int jj = 0; jj < 16; jj++) {
        int n = n0 + jj;
        uint bit = (mwv[row][n & 15] >> (n >> 4)) & 1u;
        float lv = bf2f((ushort)(jj < 8 ? v0[jj] : v1[jj - 8]));
        ov[jj] = bit ? lv - lse : NEG_INF - lse;
    }
    float* ob = out + (size_t)(r0 + row) * NN + n0;
    #pragma unroll
    for (int q = 0; q < 4; q++)
        *(float4*)(ob + q * 4) = *(float4*)(&ov[q * 4]);
}

// ---------------------------------------------------------------------------
extern "C" void kernel_launch(void* const* d_in, const int* in_sizes, int n_in,
                              void* d_out, int out_size, void* d_ws,
                              size_t ws_size, hipStream_t stream) {
    const float* emb = (const float*)d_in[0];
    const int* cur   = (const int*)d_in[1];
    const int* mask  = (const int*)d_in[2];
    const float* Wn  = (const float*)d_in[3];
    const float* Wf  = (const float*)d_in[4];
    const float* Ws  = (const float*)d_in[5];
    const float* Wo  = (const float*)d_in[6];
    float* out = (float*)d_out;

    const size_t SLABE = (size_t)BB * NN * DD;
    ushort* embB     = (ushort*)d_ws;
    ushort* gkT      = embB + SLABE;     // [bh][n][32]
    ushort* vTp      = gkT + SLABE;      // [bh][dh][n''] pre-permuted
    ushort* lkb      = vTp + SLABE;      // [b*N+n][256]
    ushort* gq       = lkb + SLABE;      // [b*T+t][256]
    ushort* headsB   = gq + SLABE;
    ushort* glimpseB = headsB + SLABE;
    ushort* WnT      = glimpseB + SLABE;
    ushort* WsT      = WnT + 768 * 256;
    ushort* WoT      = WsT + 256 * 256;
    uint*   mbt      = (uint*)(WoT + 256 * 256);
    float*  partial  = (float*)(mbt + (size_t)BB * TT * 16);
    // K5 scratch reuses embB/gkT/vTp region (dead after attn9):
    ushort* logitsB  = embB;                       // 16.8 MB
    float*  psum     = (float*)(embB + (size_t)BB * TT * NN);  // 512 KB

    prep_all_k<<<1600, 256, 0, stream>>>(emb, embB, partial, Wn, Ws, Wo,
                                         WnT, WsT, WoT, mask, mbt);
    // K1 (1536 blocks, by-inner) + K2 (512 blocks, in-block ctx) fused
    gemm3_k<0><<<2048, 256, 0, stream>>>(embB, WnT, WsT, gkT, vTp, lkb, gq,
                                         partial, Wf, cur);
    attn9_k<<<512, 256, 0, stream>>>(gq, gkT, vTp, mbt, headsB);
    // K4
    gemm3_k<1><<<512, 256, 0, stream>>>(headsB, WoT, nullptr, glimpseB,
                                        nullptr, nullptr, nullptr, nullptr,
                                        nullptr, nullptr);
    // K5: two-pass pointer logits + log_softmax
    logits_mm_k<<<1024, 256, 0, stream>>>(glimpseB, lkb, mbt, logitsB, psum);
    logits_fin_k<<<BB * TT / 8, 256, 0, stream>>>(logitsB, psum, mbt, out);
}

// Round 14
// 108.421 us; speedup vs baseline: 1.2577x; 1.1012x over previous
//
#include <hip/hip_runtime.h>
#include <hip/hip_bf16.h>

constexpr int BB = 32;    // batch
constexpr int TT = 512;   // decode steps
constexpr int NN = 512;   // nodes
constexpr int DD = 256;   // model dim
constexpr int HH = 8;     // heads
constexpr int DH = 32;    // head dim
#define NEG_INF (-1e9f)

typedef __attribute__((ext_vector_type(8))) short bf16x8;
typedef __attribute__((ext_vector_type(4))) float f32x4;

__device__ inline ushort f2bf(float x) {
    union { float f; unsigned u; } c; c.f = x;
    unsigned u = c.u + 0x7fffu + ((c.u >> 16) & 1u);  // RNE
    return (ushort)(u >> 16);
}
__device__ inline uint pk2t(float a, float b) {  // truncating pack
    return __builtin_amdgcn_perm(__float_as_uint(b), __float_as_uint(a),
                                 0x07060302u);
}
__device__ inline ushort tr16(float x) { return (ushort)(__float_as_uint(x) >> 16); }
__device__ inline float bf2f(ushort u) {
    union { uint u; float f; } c; c.u = (uint)u << 16; return c.f;
}
__device__ inline float fast_tanh10(float x) {
    x = fminf(fmaxf(x, -20.f), 20.f);
    float e2 = __expf(2.f * x);
    return 10.f * (1.f - 2.f / (e2 + 1.f));
}

// ---------------------------------------------------------------------------
// prep_all: [0,256) emb cvt+partials | [256,576) weight transposes |
//           [576,1600) mask bit-pack
__global__ __launch_bounds__(256) void prep_all_k(
    const float* __restrict__ emb, ushort* __restrict__ embB,
    float* __restrict__ partial, const float* __restrict__ Wn,
    const float* __restrict__ Ws, const float* __restrict__ Wo,
    ushort* __restrict__ WnT, ushort* __restrict__ WsT,
    ushort* __restrict__ WoT, const int* __restrict__ mask,
    uint* __restrict__ mbt) {
    int j = blockIdx.x;
    int tid = threadIdx.x;
    if (j < 256) {
        int b = j >> 3, part = j & 7, d = tid;
        const float* eb = emb + ((size_t)b * NN + part * 64) * DD + d;
        ushort* ob = embB + ((size_t)b * NN + part * 64) * DD + d;
        float s = 0.f;
        #pragma unroll 4
        for (int i = 0; i < 64; i++) {
            float v = eb[(size_t)i * DD];
            s += v;
            ob[(size_t)i * DD] = f2bf(v);
        }
        partial[((size_t)b * 8 + part) * DD + d] = s;
    } else if (j < 576) {
        __shared__ float t[32][33];
        int g = j - 256;
        int gx = g % 40, gy = g / 40;
        const float* W;
        ushort* WT;
        int NC, xb;
        if (gx < 24)      { W = Wn; WT = WnT; NC = 768; xb = gx; }
        else if (gx < 32) { W = Ws; WT = WsT; NC = 256; xb = gx - 24; }
        else              { W = Wo; WT = WoT; NC = 256; xb = gx - 32; }
        int tx = tid & 31, ty = tid >> 5;
        int x = xb * 32 + tx;
        int y0 = gy * 32;
        #pragma unroll
        for (int i = 0; i < 4; i++)
            t[ty + i * 8][tx] = W[(size_t)(y0 + ty + i * 8) * NC + x];
        __syncthreads();
        #pragma unroll
        for (int i = 0; i < 4; i++)
            WT[(size_t)(xb * 32 + ty + i * 8) * 256 + y0 + tx] =
                f2bf(t[tx][ty + i * 8]);
    } else {
        int idx = (j - 576) * 256 + tid;
        int row = idx >> 4, w = idx & 15;
        const int* mr = mask + (size_t)row * NN + w;
        uint u = 0;
        #pragma unroll
        for (int c = 0; c < 32; c++) u |= (uint)(mr[c * 16] != 0) << c;
        mbt[idx] = u;
    }
}

// ---------------------------------------------------------------------------
// gemm3: BM=128 x BN=64 x BK=64, 24KB LDS, 4 k-iters (verified r11-r13).
// XCD-CHUNKED grids (T1, corrected): XCD x = j&7 owns a contiguous set of
// A-row-panels so each panel is fetched once per its own L2.
// TASK 0: j<1536 -> K1 (x=j&7,t=j>>3: bx=x*16+t/12, by=t%12);
//         j>=1536 -> K2 (x=jj&7,t=jj>>3: bx=x*16+t/4, by=t%4; in-block ctx).
// TASK 1: K4 (x=j&7,t=j>>3: bx=x*16+t/4, by=t%4).
template <int TASK>
__global__ __launch_bounds__(256) void gemm3_k(
    const ushort* __restrict__ A0, const ushort* __restrict__ WT0,
    const ushort* __restrict__ WT1, ushort* __restrict__ O0,
    ushort* __restrict__ O1, ushort* __restrict__ O2,
    ushort* __restrict__ O3, const float* __restrict__ partial,
    const float* __restrict__ Wf, const int* __restrict__ cur) {
    int j = blockIdx.x;
    bool k2 = (TASK == 0) && (j >= 1536);
    int bx, by;
    if (TASK == 0 && !k2) {
        int x = j & 7, t = j >> 3;           // t in [0,192)
        bx = x * 16 + t / 12; by = t % 12;
    } else {
        int jj = k2 ? j - 1536 : j;
        int x = jj & 7, t = jj >> 3;         // t in [0,64)
        bx = x * 16 + (t >> 2); by = t & 3;
    }
    int row0 = bx * 128, col0 = by * 64;
    int tid = threadIdx.x;
    int w = tid >> 6, l = tid & 63;
    int lo = l & 15, hi = l >> 4;

    __shared__ ushort As[128 * 64];  // 16KB
    __shared__ ushort Bs[64 * 64];   // 8KB
    __shared__ float ctxs[64];

    const ushort* WT = k2 ? WT1 : WT0;
    const f32x4 zero = {0.f, 0.f, 0.f, 0.f};
    f32x4 acc[2][4] = {{zero, zero, zero, zero}, {zero, zero, zero, zero}};

    for (int kk = 0; kk < 4; kk++) {
        if (kk) __syncthreads();
        #pragma unroll
        for (int i = 0; i < 4; i++) {
            int u = i * 256 + tid;
            int row = u >> 3, slot = u & 7;
            int arow = row0 + row;
            const ushort* ap;
            if (k2) {
                int b = arow >> 9;
                ap = A0 + ((size_t)(b * NN + cur[arow])) * DD;
            } else {
                ap = A0 + (size_t)arow * DD;
            }
            uint4 v = *(const uint4*)(ap + kk * 64 + slot * 8);
            *(uint4*)((char*)As + row * 128 + ((slot ^ (row & 7)) << 4)) = v;
        }
        #pragma unroll
        for (int i = 0; i < 2; i++) {
            int u = i * 256 + tid;
            int row = u >> 3, slot = u & 7;
            uint4 v = *(const uint4*)(WT + (size_t)(col0 + row) * 256 + kk * 64 + slot * 8);
            *(uint4*)((char*)Bs + row * 128 + ((slot ^ (row & 7)) << 4)) = v;
        }
        __syncthreads();
        #pragma unroll
        for (int ks = 0; ks < 2; ks++) {
            int sx = ((ks * 4 + hi) ^ (lo & 7)) << 4;
            bf16x8 af0 = *(const bf16x8*)((char*)As + (w * 32 + lo) * 128 + sx);
            bf16x8 af1 = *(const bf16x8*)((char*)As + (w * 32 + 16 + lo) * 128 + sx);
            #pragma unroll
            for (int c = 0; c < 4; c++) {
                bf16x8 bf = *(const bf16x8*)((char*)Bs + (c * 16 + lo) * 128 + sx);
                acc[0][c] = __builtin_amdgcn_mfma_f32_16x16x32_bf16(af0, bf, acc[0][c], 0, 0, 0);
                acc[1][c] = __builtin_amdgcn_mfma_f32_16x16x32_bf16(af1, bf, acc[1][c], 0, 0, 0);
            }
        }
    }

    int bbq = row0 >> 9;  // batch (row panels never cross batches)
    if (k2) {
        // in-block ctx: ctx[col] = (sum_p partial[b][p][:]/512) @ Wf[:, col]
        __syncthreads();  // As free
        float* fs = (float*)As;
        float mk = 0.f;
        #pragma unroll
        for (int p = 0; p < 8; p++)
            mk += partial[(size_t)bbq * 2048 + p * 256 + tid];
        fs[tid] = mk * (1.0f / 512.0f);
        __syncthreads();
        int cc = tid & 63, part = tid >> 6;
        float cs = 0.f;
        #pragma unroll 16
        for (int k = part * 64; k < part * 64 + 64; k++)
            cs += fs[k] * Wf[(size_t)k * 256 + col0 + cc];
        float* fs2 = fs + 256;
        fs2[part * 64 + cc] = cs;
        __syncthreads();
        if (tid < 64)
            ctxs[tid] = fs2[tid] + fs2[64 + tid] + fs2[128 + tid] + fs2[192 + tid];
        __syncthreads();
    }

    #pragma unroll
    for (int rg = 0; rg < 2; rg++) {
        int rw0 = row0 + w * 32 + rg * 16;
        int bb = rw0 >> 9;
        #pragma unroll
        for (int c = 0; c < 4; c++) {
            int col = col0 + c * 16 + lo;
            float v[4];
            #pragma unroll
            for (int r = 0; r < 4; r++) v[r] = acc[rg][c][r];
            if constexpr (TASK == 0) {
                if (k2) {
                    float bv = ctxs[col - col0];
                    #pragma unroll
                    for (int r = 0; r < 4; r++)
                        O3[(size_t)(rw0 + 4 * hi + r) * DD + col] = f2bf(v[r] + bv);
                } else if (col < 256) {
                    int head = col >> 5, dh = col & 31;
                    #pragma unroll
                    for (int r = 0; r < 4; r++) {
                        int n = (rw0 + 4 * hi + r) & (NN - 1);
                        O0[(((size_t)(bb * HH + head) * NN + n) << 5) + dh] = f2bf(v[r]);
                    }
                } else if (col < 512) {
                    int cc2 = col - 256;
                    int bhv = bb * HH + (cc2 >> 5);
                    int dh = cc2 & 31;
                    int n0 = (rw0 + 4 * hi) & (NN - 1);
                    int m = n0 >> 2;
                    int p_ = m >> 3, s_ = (m >> 2) & 1, g_ = m & 3;
                    int n0p = (8 * p_ + 2 * g_ + s_) << 2;
                    ushort4 uv = {f2bf(v[0]), f2bf(v[1]), f2bf(v[2]), f2bf(v[3])};
                    *(ushort4*)(O1 + ((size_t)bhv * DH + dh) * NN + n0p) = uv;
                } else {
                    #pragma unroll
                    for (int r = 0; r < 4; r++)
                        O2[(size_t)(rw0 + 4 * hi + r) * 256 + (col - 512)] = f2bf(v[r]);
                }
            } else {
                #pragma unroll
                for (int r = 0; r < 4; r++)
                    O0[(size_t)(rw0 + 4 * hi + r) * DD + col] = f2bf(v[r]);
            }
        }
    }
}

// ---------------------------------------------------------------------------
// K3: two-phase LDS-staged swapped-operand attention, 128 q-rows/block.
// grid 1024: bh = j&255 (same-bh blocks co-XCD since 256%8==0), quarter=j>>8.
// 37KB LDS + <=128 VGPR -> 4 blocks/CU. No-max softmax => phases accumulate.
__global__ __launch_bounds__(256, 4) void attn10_k(
    const ushort* __restrict__ gq, const ushort* __restrict__ gkT,
    const ushort* __restrict__ vTp, const uint* __restrict__ mbt,
    ushort* __restrict__ headsB) {
    int j = blockIdx.x;
    int bh = j & 255, quarter = j >> 8;
    int b = bh >> 3, h = bh & 7;
    int tid = threadIdx.x;
    int w = tid >> 6, l = tid & 63;
    int lo = l & 15, hi = l >> 4;

    __shared__ ushort Ks[8192];       // 16KB: 256 n-rows x 64B, ^((n&7)<<4)
    __shared__ ushort Vs[8192];       // 16KB: 32 dh-rows x 512B, ^((dh&7)<<4)
    __shared__ ushort OT[4][16][40];  // 5KB transpose staging

    const f32x4 zero = {0.f, 0.f, 0.f, 0.f};
    const bf16x8 ones = {(short)0x3F80, (short)0x3F80, (short)0x3F80,
                         (short)0x3F80, (short)0x3F80, (short)0x3F80,
                         (short)0x3F80, (short)0x3F80};
    const float sc = 0.17677669529663687f;  // 1/sqrt(32)
    int q0 = quarter * 128;
    int kswz = (lo & 7) << 4;

    f32x4 o0[2] = {zero, zero};
    f32x4 o1[2] = {zero, zero};
    f32x4 osum[2] = {zero, zero};

    const char* kbase = (const char*)(gkT + (size_t)bh * (NN * DH));
    const char* vbase = (const char*)(vTp + (size_t)bh * (DH * NN));

    for (int ph = 0; ph < 2; ph++) {
        if (ph) __syncthreads();
        {
            const char* ksrc = kbase + ph * 16384;
            #pragma unroll
            for (int i = 0; i < 4; i++) {
                int u = i * 256 + tid;
                int nn = u >> 2, slot = u & 3;
                uint4 v = *(const uint4*)(ksrc + nn * 64 + slot * 16);
                *(uint4*)((char*)Ks + ((nn * 64 + slot * 16) ^ ((nn & 7) << 4))) = v;
            }
        }
        {
            const char* vsrc = vbase + ph * 512;
            #pragma unroll
            for (int i = 0; i < 4; i++) {
                int u = i * 256 + tid;
                int dh = u >> 5, slot = u & 31;
                uint4 v = *(const uint4*)(vsrc + dh * 1024 + slot * 16);
                *(uint4*)((char*)Vs + ((dh * 512 + slot * 16) ^ ((dh & 7) << 4))) = v;
            }
        }
        __syncthreads();

        #pragma unroll
        for (int qc2 = 0; qc2 < 2; qc2++) {
            int t0 = q0 + qc2 * 64 + w * 16;
            bf16x8 qf = *(const bf16x8*)(gq + ((size_t)(b * TT + t0 + lo)) * DD + h * DH + hi * 8);
            uint4 mq = *(const uint4*)(mbt + ((size_t)(b * TT + t0 + lo)) * 16 + 4 * hi);

            #pragma unroll 4
            for (int p = 0; p < 8; p++) {
                int nn = 32 * p + lo;
                bf16x8 kf0 = *(const bf16x8*)((char*)Ks + ((nn * 64 + hi * 16) ^ kswz));
                bf16x8 kf1 = *(const bf16x8*)((char*)Ks + (((nn + 16) * 64 + hi * 16) ^ kswz));
                f32x4 s0 = __builtin_amdgcn_mfma_f32_16x16x32_bf16(kf0, qf, zero, 0, 0, 0);
                f32x4 s1 = __builtin_amdgcn_mfma_f32_16x16x32_bf16(kf1, qf, zero, 0, 0, 0);
                union { bf16x8 v; uint u[4]; } pf;
                {
                    int c = ph * 16 + 2 * p;
                    float e0 = ((mq.x >> c) & 1u) ? __expf(s0[0] * sc) : 0.f;
                    float e1 = ((mq.y >> c) & 1u) ? __expf(s0[1] * sc) : 0.f;
                    float e2 = ((mq.z >> c) & 1u) ? __expf(s0[2] * sc) : 0.f;
                    float e3 = ((mq.w >> c) & 1u) ? __expf(s0[3] * sc) : 0.f;
                    pf.u[0] = pk2t(e0, e1);
                    pf.u[1] = pk2t(e2, e3);
                }
                {
                    int c = ph * 16 + 2 * p + 1;
                    float e0 = ((mq.x >> c) & 1u) ? __expf(s1[0] * sc) : 0.f;
                    float e1 = ((mq.y >> c) & 1u) ? __expf(s1[1] * sc) : 0.f;
                    float e2 = ((mq.z >> c) & 1u) ? __expf(s1[2] * sc) : 0.f;
                    float e3 = ((mq.w >> c) & 1u) ? __expf(s1[3] * sc) : 0.f;
                    pf.u[2] = pk2t(e0, e1);
                    pf.u[3] = pk2t(e2, e3);
                }
                int vo = (32 * p + 8 * hi) * 2;
                bf16x8 va0 = *(const bf16x8*)((char*)Vs + ((lo * 512 + vo) ^ kswz));
                bf16x8 va1 = *(const bf16x8*)((char*)Vs + (((lo + 16) * 512 + vo) ^ kswz));
                o0[qc2] = __builtin_amdgcn_mfma_f32_16x16x32_bf16(va0, pf.v, o0[qc2], 0, 0, 0);
                o1[qc2] = __builtin_amdgcn_mfma_f32_16x16x32_bf16(va1, pf.v, o1[qc2], 0, 0, 0);
                osum[qc2] = __builtin_amdgcn_mfma_f32_16x16x32_bf16(ones, pf.v, osum[qc2], 0, 0, 0);
            }
        }
    }

    #pragma unroll
    for (int qc2 = 0; qc2 < 2; qc2++) {
        int t0 = q0 + qc2 * 64 + w * 16;
        float inv = 1.0f / fmaxf(osum[qc2][0], 1e-30f);
        #pragma unroll
        for (int r = 0; r < 4; r++) {
            OT[w][lo][4 * hi + r] = tr16(o0[qc2][r] * inv);
            OT[w][lo][16 + 4 * hi + r] = tr16(o1[qc2][r] * inv);
        }
        bf16x8 ov = *(const bf16x8*)(&OT[w][lo][hi * 8]);
        *(bf16x8*)(headsB + ((size_t)(b * TT + t0 + lo)) * DD + h * DH + hi * 8) = ov;
    }
}

// ---------------------------------------------------------------------------
// K5a: pointer-logits GEMM -> bf16 logits + per-(row, col-panel) masked
// exp-sum partials. XCD-chunked: x=j&7 owns 4 batches (lk L2-resident).
__global__ __launch_bounds__(256) void logits_mm_k(
    const ushort* __restrict__ glimpse, const ushort* __restrict__ lkb,
    const uint* __restrict__ mbt, ushort* __restrict__ logitsB,
    float* __restrict__ psum) {
    int j = blockIdx.x;  // 1024
    int x = j & 7, t = j >> 3;       // t in [0,128)
    int b = x * 4 + (t >> 5);
    int rem = t & 31;
    int bx = rem >> 3, by = rem & 7;
    int row0 = bx * 128, col0 = by * 64;
    int tid = threadIdx.x;
    int w = tid >> 6, l = tid & 63;
    int lo = l & 15, hi = l >> 4;

    __shared__ ushort As[128 * 64];
    __shared__ ushort Bs[64 * 64];

    const ushort* Abase = glimpse + (size_t)b * TT * DD;
    const ushort* Bbase = lkb + (size_t)b * NN * DD;

    const f32x4 zero = {0.f, 0.f, 0.f, 0.f};
    f32x4 acc[2][4] = {{zero, zero, zero, zero}, {zero, zero, zero, zero}};

    for (int kk = 0; kk < 4; kk++) {
        if (kk) __syncthreads();
        #pragma unroll
        for (int i = 0; i < 4; i++) {
            int u = i * 256 + tid;
            int row = u >> 3, slot = u & 7;
            uint4 v = *(const uint4*)(Abase + (size_t)(row0 + row) * DD + kk * 64 + slot * 8);
            *(uint4*)((char*)As + row * 128 + ((slot ^ (row & 7)) << 4)) = v;
        }
        #pragma unroll
        for (int i = 0; i < 2; i++) {
            int u = i * 256 + tid;
            int row = u >> 3, slot = u & 7;
            uint4 v = *(const uint4*)(Bbase + (size_t)(col0 + row) * DD + kk * 64 + slot * 8);
            *(uint4*)((char*)Bs + row * 128 + ((slot ^ (row & 7)) << 4)) = v;
        }
        __syncthreads();
        #pragma unroll
        for (int ks = 0; ks < 2; ks++) {
            int sx = ((ks * 4 + hi) ^ (lo & 7)) << 4;
            bf16x8 af0 = *(const bf16x8*)((char*)As + (w * 32 + lo) * 128 + sx);
            bf16x8 af1 = *(const bf16x8*)((char*)As + (w * 32 + 16 + lo) * 128 + sx);
            #pragma unroll
            for (int c = 0; c < 4; c++) {
                bf16x8 bf = *(const bf16x8*)((char*)Bs + (c * 16 + lo) * 128 + sx);
                acc[0][c] = __builtin_amdgcn_mfma_f32_16x16x32_bf16(af0, bf, acc[0][c], 0, 0, 0);
                acc[1][c] = __builtin_amdgcn_mfma_f32_16x16x32_bf16(af1, bf, acc[1][c], 0, 0, 0);
            }
        }
    }

    #pragma unroll
    for (int rg = 0; rg < 2; rg++) {
        int rw = row0 + w * 32 + rg * 16;
        uint mw[4];
        #pragma unroll
        for (int r = 0; r < 4; r++)
            mw[r] = mbt[((size_t)(b * TT + rw + 4 * hi + r)) * 16 + lo];
        float rsum[4] = {0.f, 0.f, 0.f, 0.f};
        #pragma unroll
        for (int c = 0; c < 4; c++) {
            int col = col0 + c * 16 + lo;
            int cg = by * 4 + c;
            #pragma unroll
            for (int r = 0; r < 4; r++) {
                float t2 = fast_tanh10(acc[rg][c][r] * 0.0625f);
                logitsB[((size_t)(b * TT + rw + 4 * hi + r)) * NN + col] = tr16(t2);
                rsum[r] += ((mw[r] >> cg) & 1u) ? __expf(t2 - 10.f) : 0.f;
            }
        }
        #pragma unroll
        for (int r = 0; r < 4; r++) {
            #pragma unroll
            for (int o = 1; o < 16; o <<= 1) rsum[r] += __shfl_xor(rsum[r], o);
        }
        if (lo == 0) {
            #pragma unroll
            for (int r = 0; r < 4; r++)
                psum[((size_t)(b * TT + rw + 4 * hi + r)) * 8 + by] = rsum[r];
        }
    }
}

// K5b: out = (mask ? logit : NEG_INF) - lse, lse = 10 + log(sum8 psum).
__global__ __launch_bounds__(256) void logits_fin_k(
    const ushort* __restrict__ logitsB, const float* __restrict__ psum,
    const uint* __restrict__ mbt, float* __restrict__ out) {
    int r0 = blockIdx.x * 8;
    int tid = threadIdx.x;
    __shared__ float lsev[8];
    __shared__ uint mwv[8][16];
    if (tid < 128) {
        mwv[tid >> 4][tid & 15] = mbt[(size_t)(r0 + (tid >> 4)) * 16 + (tid & 15)];
    } else if (tid < 136) {
        int rr = tid - 128;
        const float* pp = psum + (size_t)(r0 + rr) * 8;
        float s = 0.f;
        #pragma unroll
        for (int p = 0; p < 8; p++) s += pp[p];
        lsev[rr] = 10.f + __logf(fmaxf(s, 1e-37f));
    }
    __syncthreads();
    int row = tid >> 5, n0 = (tid & 31) * 16;
    float lse = lsev[row];
    const ushort* lb = logitsB + (size_t)(r0 + row) * NN + n0;
    bf16x8 v0 = *(const bf16x8*)(lb);
    bf16x8 v1 = *(const bf16x8*)(lb + 8);
    float ov[16];
    #pragma unroll
    for (int jj = 0; jj < 16; jj++) {
        int n = n0 + jj;
        uint bit = (mwv[row][n & 15] >> (n >> 4)) & 1u;
        float lv = bf2f((ushort)(jj < 8 ? v0[jj] : v1[jj - 8]));
        ov[jj] = bit ? lv - lse : NEG_INF - lse;
    }
    float* ob = out + (size_t)(r0 + row) * NN + n0;
    #pragma unroll
    for (int q = 0; q < 4; q++)
        *(float4*)(ob + q * 4) = *(float4*)(&ov[q * 4]);
}

// ---------------------------------------------------------------------------
extern "C" void kernel_launch(void* const* d_in, const int* in_sizes, int n_in,
                              void* d_out, int out_size, void* d_ws,
                              size_t ws_size, hipStream_t stream) {
    const float* emb = (const float*)d_in[0];
    const int* cur   = (const int*)d_in[1];
    const int* mask  = (const int*)d_in[2];
    const float* Wn  = (const float*)d_in[3];
    const float* Wf  = (const float*)d_in[4];
    const float* Ws  = (const float*)d_in[5];
    const float* Wo  = (const float*)d_in[6];
    float* out = (float*)d_out;

    const size_t SLABE = (size_t)BB * NN * DD;
    ushort* embB     = (ushort*)d_ws;
    ushort* gkT      = embB + SLABE;     // [bh][n][32]
    ushort* vTp      = gkT + SLABE;      // [bh][dh][n''] pre-permuted
    ushort* lkb      = vTp + SLABE;      // [b*N+n][256]
    ushort* gq       = lkb + SLABE;      // [b*T+t][256]
    ushort* headsB   = gq + SLABE;
    ushort* glimpseB = headsB + SLABE;
    ushort* WnT      = glimpseB + SLABE;
    ushort* WsT      = WnT + 768 * 256;
    ushort* WoT      = WsT + 256 * 256;
    uint*   mbt      = (uint*)(WoT + 256 * 256);
    float*  partial  = (float*)(mbt + (size_t)BB * TT * 16);
    // K5 scratch reuses embB/gkT/vTp region (dead after attn10):
    ushort* logitsB  = embB;                       // 16.8 MB
    float*  psum     = (float*)(embB + (size_t)BB * TT * NN);  // 512 KB

    prep_all_k<<<1600, 256, 0, stream>>>(emb, embB, partial, Wn, Ws, Wo,
                                         WnT, WsT, WoT, mask, mbt);
    // K1 (1536 blocks) + K2 (512 blocks) fused, XCD-chunked
    gemm3_k<0><<<2048, 256, 0, stream>>>(embB, WnT, WsT, gkT, vTp, lkb, gq,
                                         partial, Wf, cur);
    attn10_k<<<1024, 256, 0, stream>>>(gq, gkT, vTp, mbt, headsB);
    // K4, XCD-chunked
    gemm3_k<1><<<512, 256, 0, stream>>>(headsB, WoT, nullptr, glimpseB,
                                        nullptr, nullptr, nullptr, nullptr,
                                        nullptr, nullptr);
    // K5: two-pass pointer logits + log_softmax
    logits_mm_k<<<1024, 256, 0, stream>>>(glimpseB, lkb, mbt, logitsB, psum);
    logits_fin_k<<<BB * TT / 8, 256, 0, stream>>>(logitsB, psum, mbt, out);
}

// Round 15
// 102.458 us; speedup vs baseline: 1.3309x; 1.0582x over previous
//
#include <hip/hip_runtime.h>
#include <hip/hip_bf16.h>

constexpr int BB = 32;    // batch
constexpr int TT = 512;   // decode steps
constexpr int NN = 512;   // nodes
constexpr int DD = 256;   // model dim
constexpr int HH = 8;     // heads
constexpr int DH = 32;    // head dim
#define NEG_INF (-1e9f)

typedef __attribute__((ext_vector_type(8))) short bf16x8;
typedef __attribute__((ext_vector_type(4))) float f32x4;

__device__ inline ushort f2bf(float x) {
    union { float f; unsigned u; } c; c.f = x;
    unsigned u = c.u + 0x7fffu + ((c.u >> 16) & 1u);  // RNE
    return (ushort)(u >> 16);
}
__device__ inline uint pk2t(float a, float b) {  // truncating pack
    return __builtin_amdgcn_perm(__float_as_uint(b), __float_as_uint(a),
                                 0x07060302u);
}
__device__ inline ushort tr16(float x) { return (ushort)(__float_as_uint(x) >> 16); }
__device__ inline float bf2f(ushort u) {
    union { uint u; float f; } c; c.u = (uint)u << 16; return c.f;
}
__device__ inline float fast_tanh10(float x) {
    x = fminf(fmaxf(x, -20.f), 20.f);
    float e2 = __expf(2.f * x);
    return 10.f * (1.f - 2.f / (e2 + 1.f));
}
// async global->LDS, 16B per lane; dest = wave-uniform base + lane*16,
// source is per-lane (pre-swizzled), m97/m173 pattern.
__device__ inline void gload_lds16(const void* g, void* l) {
    __builtin_amdgcn_global_load_lds(
        (const __attribute__((address_space(1))) unsigned int*)g,
        (__attribute__((address_space(3))) unsigned int*)l, 16, 0, 0);
}

// ---------------------------------------------------------------------------
// prep_all: [0,256) emb cvt+partials | [256,576) weight transposes |
//           [576,1600) mask bit-pack
__global__ __launch_bounds__(256) void prep_all_k(
    const float* __restrict__ emb, ushort* __restrict__ embB,
    float* __restrict__ partial, const float* __restrict__ Wn,
    const float* __restrict__ Ws, const float* __restrict__ Wo,
    ushort* __restrict__ WnT, ushort* __restrict__ WsT,
    ushort* __restrict__ WoT, const int* __restrict__ mask,
    uint* __restrict__ mbt) {
    int j = blockIdx.x;
    int tid = threadIdx.x;
    if (j < 256) {
        int b = j >> 3, part = j & 7, d = tid;
        const float* eb = emb + ((size_t)b * NN + part * 64) * DD + d;
        ushort* ob = embB + ((size_t)b * NN + part * 64) * DD + d;
        float s = 0.f;
        #pragma unroll 4
        for (int i = 0; i < 64; i++) {
            float v = eb[(size_t)i * DD];
            s += v;
            ob[(size_t)i * DD] = f2bf(v);
        }
        partial[((size_t)b * 8 + part) * DD + d] = s;
    } else if (j < 576) {
        __shared__ float t[32][33];
        int g = j - 256;
        int gx = g % 40, gy = g / 40;
        const float* W;
        ushort* WT;
        int NC, xb;
        if (gx < 24)      { W = Wn; WT = WnT; NC = 768; xb = gx; }
        else if (gx < 32) { W = Ws; WT = WsT; NC = 256; xb = gx - 24; }
        else              { W = Wo; WT = WoT; NC = 256; xb = gx - 32; }
        int tx = tid & 31, ty = tid >> 5;
        int x = xb * 32 + tx;
        int y0 = gy * 32;
        #pragma unroll
        for (int i = 0; i < 4; i++)
            t[ty + i * 8][tx] = W[(size_t)(y0 + ty + i * 8) * NC + x];
        __syncthreads();
        #pragma unroll
        for (int i = 0; i < 4; i++)
            WT[(size_t)(xb * 32 + ty + i * 8) * 256 + y0 + tx] =
                f2bf(t[tx][ty + i * 8]);
    } else {
        int idx = (j - 576) * 256 + tid;
        int row = idx >> 4, w = idx & 15;
        const int* mr = mask + (size_t)row * NN + w;
        uint u = 0;
        #pragma unroll
        for (int c = 0; c < 32; c++) u |= (uint)(mr[c * 16] != 0) << c;
        mbt[idx] = u;
    }
}

// ---------------------------------------------------------------------------
// gemm3: BM=128 x BN=64 x BK=64, DOUBLE-BUFFERED async staging via
// global_load_lds (linear LDS dest + source-side XOR swizzle; reads use the
// same swizzled addrs as r11-r14). 48KB LDS -> 3 blocks/CU. XCD-chunked.
// TASK 0: j<1536 -> K1 (proj -> gkT/vTp/lk); j>=1536 -> K2 (gq, in-block ctx).
// TASK 1: K4 (glimpse = heads @ Wo).
template <int TASK>
__global__ __launch_bounds__(256) void gemm3_k(
    const ushort* __restrict__ A0, const ushort* __restrict__ WT0,
    const ushort* __restrict__ WT1, ushort* __restrict__ O0,
    ushort* __restrict__ O1, ushort* __restrict__ O2,
    ushort* __restrict__ O3, const float* __restrict__ partial,
    const float* __restrict__ Wf, const int* __restrict__ cur) {
    int j = blockIdx.x;
    bool k2 = (TASK == 0) && (j >= 1536);
    int bx, by;
    if (TASK == 0 && !k2) {
        int x = j & 7, t = j >> 3;           // t in [0,192)
        bx = x * 16 + t / 12; by = t % 12;
    } else {
        int jj = k2 ? j - 1536 : j;
        int x = jj & 7, t = jj >> 3;         // t in [0,64)
        bx = x * 16 + (t >> 2); by = t & 3;
    }
    int row0 = bx * 128, col0 = by * 64;
    int tid = threadIdx.x;
    int w = tid >> 6, l = tid & 63;
    int lo = l & 15, hi = l >> 4;

    __shared__ ushort As[2][128 * 64];  // 2 x 16KB
    __shared__ ushort Bs[2][64 * 64];   // 2 x 8KB
    __shared__ float ctxs[64];

    const ushort* WT = k2 ? WT1 : WT0;

    // async stage of k-tile kk into buffer buf (source pre-swizzled)
    auto stage = [&](int buf, int kk) {
        #pragma unroll
        for (int i = 0; i < 4; i++) {
            int u = i * 256 + tid;
            int row = u >> 3, slot = u & 7;
            int arow = row0 + row;
            const ushort* ap;
            if (k2) {
                int b = arow >> 9;
                ap = A0 + ((size_t)(b * NN + cur[arow])) * DD;
            } else {
                ap = A0 + (size_t)arow * DD;
            }
            const void* gsrc = ap + kk * 64 + ((slot ^ (row & 7)) << 3);
            void* ldst = (char*)&As[buf][0] + i * 4096 + w * 1024;
            gload_lds16(gsrc, ldst);
        }
        #pragma unroll
        for (int i = 0; i < 2; i++) {
            int u = i * 256 + tid;
            int row = u >> 3, slot = u & 7;
            const void* gsrc =
                WT + (size_t)(col0 + row) * 256 + kk * 64 + ((slot ^ (row & 7)) << 3);
            void* ldst = (char*)&Bs[buf][0] + i * 4096 + w * 1024;
            gload_lds16(gsrc, ldst);
        }
    };

    const f32x4 zero = {0.f, 0.f, 0.f, 0.f};
    f32x4 acc[2][4] = {{zero, zero, zero, zero}, {zero, zero, zero, zero}};

    stage(0, 0);
    __syncthreads();
    #pragma unroll
    for (int kk = 0; kk < 4; kk++) {
        if (kk < 3) stage((kk + 1) & 1, kk + 1);  // stays in flight over MFMAs
        int cb = kk & 1;
        #pragma unroll
        for (int ks = 0; ks < 2; ks++) {
            int sx = ((ks * 4 + hi) ^ (lo & 7)) << 4;
            bf16x8 af0 = *(const bf16x8*)((char*)&As[cb][0] + (w * 32 + lo) * 128 + sx);
            bf16x8 af1 = *(const bf16x8*)((char*)&As[cb][0] + (w * 32 + 16 + lo) * 128 + sx);
            #pragma unroll
            for (int c = 0; c < 4; c++) {
                bf16x8 bf = *(const bf16x8*)((char*)&Bs[cb][0] + (c * 16 + lo) * 128 + sx);
                acc[0][c] = __builtin_amdgcn_mfma_f32_16x16x32_bf16(af0, bf, acc[0][c], 0, 0, 0);
                acc[1][c] = __builtin_amdgcn_mfma_f32_16x16x32_bf16(af1, bf, acc[1][c], 0, 0, 0);
            }
        }
        __syncthreads();  // drains staged loads; next buffer ready
    }

    int bbq = row0 >> 9;  // batch (row panels never cross batches)
    if (k2) {
        // in-block ctx: ctx[col] = (sum_p partial[b][p][:]/512) @ Wf[:, col]
        float* fs = (float*)&As[0][0];
        float mk = 0.f;
        #pragma unroll
        for (int p = 0; p < 8; p++)
            mk += partial[(size_t)bbq * 2048 + p * 256 + tid];
        fs[tid] = mk * (1.0f / 512.0f);
        __syncthreads();
        int cc = tid & 63, part = tid >> 6;
        float cs = 0.f;
        #pragma unroll 16
        for (int k = part * 64; k < part * 64 + 64; k++)
            cs += fs[k] * Wf[(size_t)k * 256 + col0 + cc];
        float* fs2 = fs + 256;
        fs2[part * 64 + cc] = cs;
        __syncthreads();
        if (tid < 64)
            ctxs[tid] = fs2[tid] + fs2[64 + tid] + fs2[128 + tid] + fs2[192 + tid];
        __syncthreads();
    }

    #pragma unroll
    for (int rg = 0; rg < 2; rg++) {
        int rw0 = row0 + w * 32 + rg * 16;
        int bb = rw0 >> 9;
        #pragma unroll
        for (int c = 0; c < 4; c++) {
            int col = col0 + c * 16 + lo;
            float v[4];
            #pragma unroll
            for (int r = 0; r < 4; r++) v[r] = acc[rg][c][r];
            if constexpr (TASK == 0) {
                if (k2) {
                    float bv = ctxs[col - col0];
                    #pragma unroll
                    for (int r = 0; r < 4; r++)
                        O3[(size_t)(rw0 + 4 * hi + r) * DD + col] = f2bf(v[r] + bv);
                } else if (col < 256) {
                    int head = col >> 5, dh = col & 31;
                    #pragma unroll
                    for (int r = 0; r < 4; r++) {
                        int n = (rw0 + 4 * hi + r) & (NN - 1);
                        O0[(((size_t)(bb * HH + head) * NN + n) << 5) + dh] = f2bf(v[r]);
                    }
                } else if (col < 512) {
                    int cc2 = col - 256;
                    int bhv = bb * HH + (cc2 >> 5);
                    int dh = cc2 & 31;
                    int n0 = (rw0 + 4 * hi) & (NN - 1);
                    int m = n0 >> 2;
                    int p_ = m >> 3, s_ = (m >> 2) & 1, g_ = m & 3;
                    int n0p = (8 * p_ + 2 * g_ + s_) << 2;
                    ushort4 uv = {f2bf(v[0]), f2bf(v[1]), f2bf(v[2]), f2bf(v[3])};
                    *(ushort4*)(O1 + ((size_t)bhv * DH + dh) * NN + n0p) = uv;
                } else {
                    #pragma unroll
                    for (int r = 0; r < 4; r++)
                        O2[(size_t)(rw0 + 4 * hi + r) * 256 + (col - 512)] = f2bf(v[r]);
                }
            } else {
                #pragma unroll
                for (int r = 0; r < 4; r++)
                    O0[(size_t)(rw0 + 4 * hi + r) * DD + col] = f2bf(v[r]);
            }
        }
    }
}

// ---------------------------------------------------------------------------
// K3: two-phase LDS-staged swapped-operand attention, 128 q-rows/block
// (verified r14). 4 blocks/CU.
__global__ __launch_bounds__(256, 4) void attn10_k(
    const ushort* __restrict__ gq, const ushort* __restrict__ gkT,
    const ushort* __restrict__ vTp, const uint* __restrict__ mbt,
    ushort* __restrict__ headsB) {
    int j = blockIdx.x;
    int bh = j & 255, quarter = j >> 8;
    int b = bh >> 3, h = bh & 7;
    int tid = threadIdx.x;
    int w = tid >> 6, l = tid & 63;
    int lo = l & 15, hi = l >> 4;

    __shared__ ushort Ks[8192];       // 16KB: 256 n-rows x 64B, ^((n&7)<<4)
    __shared__ ushort Vs[8192];       // 16KB: 32 dh-rows x 512B, ^((dh&7)<<4)
    __shared__ ushort OT[4][16][40];  // 5KB transpose staging

    const f32x4 zero = {0.f, 0.f, 0.f, 0.f};
    const bf16x8 ones = {(short)0x3F80, (short)0x3F80, (short)0x3F80,
                         (short)0x3F80, (short)0x3F80, (short)0x3F80,
                         (short)0x3F80, (short)0x3F80};
    const float sc = 0.17677669529663687f;  // 1/sqrt(32)
    int q0 = quarter * 128;
    int kswz = (lo & 7) << 4;

    f32x4 o0[2] = {zero, zero};
    f32x4 o1[2] = {zero, zero};
    f32x4 osum[2] = {zero, zero};

    const char* kbase = (const char*)(gkT + (size_t)bh * (NN * DH));
    const char* vbase = (const char*)(vTp + (size_t)bh * (DH * NN));

    for (int ph = 0; ph < 2; ph++) {
        if (ph) __syncthreads();
        {
            const char* ksrc = kbase + ph * 16384;
            #pragma unroll
            for (int i = 0; i < 4; i++) {
                int u = i * 256 + tid;
                int nn = u >> 2, slot = u & 3;
                uint4 v = *(const uint4*)(ksrc + nn * 64 + slot * 16);
                *(uint4*)((char*)Ks + ((nn * 64 + slot * 16) ^ ((nn & 7) << 4))) = v;
            }
        }
        {
            const char* vsrc = vbase + ph * 512;
            #pragma unroll
            for (int i = 0; i < 4; i++) {
                int u = i * 256 + tid;
                int dh = u >> 5, slot = u & 31;
                uint4 v = *(const uint4*)(vsrc + dh * 1024 + slot * 16);
                *(uint4*)((char*)Vs + ((dh * 512 + slot * 16) ^ ((dh & 7) << 4))) = v;
            }
        }
        __syncthreads();

        #pragma unroll
        for (int qc2 = 0; qc2 < 2; qc2++) {
            int t0 = q0 + qc2 * 64 + w * 16;
            bf16x8 qf = *(const bf16x8*)(gq + ((size_t)(b * TT + t0 + lo)) * DD + h * DH + hi * 8);
            uint4 mq = *(const uint4*)(mbt + ((size_t)(b * TT + t0 + lo)) * 16 + 4 * hi);

            #pragma unroll 4
            for (int p = 0; p < 8; p++) {
                int nn = 32 * p + lo;
                bf16x8 kf0 = *(const bf16x8*)((char*)Ks + ((nn * 64 + hi * 16) ^ kswz));
                bf16x8 kf1 = *(const bf16x8*)((char*)Ks + (((nn + 16) * 64 + hi * 16) ^ kswz));
                f32x4 s0 = __builtin_amdgcn_mfma_f32_16x16x32_bf16(kf0, qf, zero, 0, 0, 0);
                f32x4 s1 = __builtin_amdgcn_mfma_f32_16x16x32_bf16(kf1, qf, zero, 0, 0, 0);
                union { bf16x8 v; uint u[4]; } pf;
                {
                    int c = ph * 16 + 2 * p;
                    float e0 = ((mq.x >> c) & 1u) ? __expf(s0[0] * sc) : 0.f;
                    float e1 = ((mq.y >> c) & 1u) ? __expf(s0[1] * sc) : 0.f;
                    float e2 = ((mq.z >> c) & 1u) ? __expf(s0[2] * sc) : 0.f;
                    float e3 = ((mq.w >> c) & 1u) ? __expf(s0[3] * sc) : 0.f;
                    pf.u[0] = pk2t(e0, e1);
                    pf.u[1] = pk2t(e2, e3);
                }
                {
                    int c = ph * 16 + 2 * p + 1;
                    float e0 = ((mq.x >> c) & 1u) ? __expf(s1[0] * sc) : 0.f;
                    float e1 = ((mq.y >> c) & 1u) ? __expf(s1[1] * sc) : 0.f;
                    float e2 = ((mq.z >> c) & 1u) ? __expf(s1[2] * sc) : 0.f;
                    float e3 = ((mq.w >> c) & 1u) ? __expf(s1[3] * sc) : 0.f;
                    pf.u[2] = pk2t(e0, e1);
                    pf.u[3] = pk2t(e2, e3);
                }
                int vo = (32 * p + 8 * hi) * 2;
                bf16x8 va0 = *(const bf16x8*)((char*)Vs + ((lo * 512 + vo) ^ kswz));
                bf16x8 va1 = *(const bf16x8*)((char*)Vs + (((lo + 16) * 512 + vo) ^ kswz));
                o0[qc2] = __builtin_amdgcn_mfma_f32_16x16x32_bf16(va0, pf.v, o0[qc2], 0, 0, 0);
                o1[qc2] = __builtin_amdgcn_mfma_f32_16x16x32_bf16(va1, pf.v, o1[qc2], 0, 0, 0);
                osum[qc2] = __builtin_amdgcn_mfma_f32_16x16x32_bf16(ones, pf.v, osum[qc2], 0, 0, 0);
            }
        }
    }

    #pragma unroll
    for (int qc2 = 0; qc2 < 2; qc2++) {
        int t0 = q0 + qc2 * 64 + w * 16;
        float inv = 1.0f / fmaxf(osum[qc2][0], 1e-30f);
        #pragma unroll
        for (int r = 0; r < 4; r++) {
            OT[w][lo][4 * hi + r] = tr16(o0[qc2][r] * inv);
            OT[w][lo][16 + 4 * hi + r] = tr16(o1[qc2][r] * inv);
        }
        bf16x8 ov = *(const bf16x8*)(&OT[w][lo][hi * 8]);
        *(bf16x8*)(headsB + ((size_t)(b * TT + t0 + lo)) * DD + h * DH + hi * 8) = ov;
    }
}

// ---------------------------------------------------------------------------
// K5a: pointer-logits GEMM, double-buffered async staging (same scheme).
// XCD-chunked: x=j&7 owns 4 batches (lk L2-resident).
__global__ __launch_bounds__(256) void logits_mm_k(
    const ushort* __restrict__ glimpse, const ushort* __restrict__ lkb,
    const uint* __restrict__ mbt, ushort* __restrict__ logitsB,
    float* __restrict__ psum) {
    int j = blockIdx.x;  // 1024
    int x = j & 7, t = j >> 3;       // t in [0,128)
    int b = x * 4 + (t >> 5);
    int rem = t & 31;
    int bx = rem >> 3, by = rem & 7;
    int row0 = bx * 128, col0 = by * 64;
    int tid = threadIdx.x;
    int w = tid >> 6, l = tid & 63;
    int lo = l & 15, hi = l >> 4;

    __shared__ ushort As[2][128 * 64];
    __shared__ ushort Bs[2][64 * 64];

    const ushort* Abase = glimpse + (size_t)b * TT * DD;
    const ushort* Bbase = lkb + (size_t)b * NN * DD;

    auto stage = [&](int buf, int kk) {
        #pragma unroll
        for (int i = 0; i < 4; i++) {
            int u = i * 256 + tid;
            int row = u >> 3, slot = u & 7;
            const void* gsrc =
                Abase + (size_t)(row0 + row) * DD + kk * 64 + ((slot ^ (row & 7)) << 3);
            void* ldst = (char*)&As[buf][0] + i * 4096 + w * 1024;
            gload_lds16(gsrc, ldst);
        }
        #pragma unroll
        for (int i = 0; i < 2; i++) {
            int u = i * 256 + tid;
            int row = u >> 3, slot = u & 7;
            const void* gsrc =
                Bbase + (size_t)(col0 + row) * DD + kk * 64 + ((slot ^ (row & 7)) << 3);
            void* ldst = (char*)&Bs[buf][0] + i * 4096 + w * 1024;
            gload_lds16(gsrc, ldst);
        }
    };

    const f32x4 zero = {0.f, 0.f, 0.f, 0.f};
    f32x4 acc[2][4] = {{zero, zero, zero, zero}, {zero, zero, zero, zero}};

    stage(0, 0);
    __syncthreads();
    #pragma unroll
    for (int kk = 0; kk < 4; kk++) {
        if (kk < 3) stage((kk + 1) & 1, kk + 1);
        int cb = kk & 1;
        #pragma unroll
        for (int ks = 0; ks < 2; ks++) {
            int sx = ((ks * 4 + hi) ^ (lo & 7)) << 4;
            bf16x8 af0 = *(const bf16x8*)((char*)&As[cb][0] + (w * 32 + lo) * 128 + sx);
            bf16x8 af1 = *(const bf16x8*)((char*)&As[cb][0] + (w * 32 + 16 + lo) * 128 + sx);
            #pragma unroll
            for (int c = 0; c < 4; c++) {
                bf16x8 bf = *(const bf16x8*)((char*)&Bs[cb][0] + (c * 16 + lo) * 128 + sx);
                acc[0][c] = __builtin_amdgcn_mfma_f32_16x16x32_bf16(af0, bf, acc[0][c], 0, 0, 0);
                acc[1][c] = __builtin_amdgcn_mfma_f32_16x16x32_bf16(af1, bf, acc[1][c], 0, 0, 0);
            }
        }
        __syncthreads();
    }

    #pragma unroll
    for (int rg = 0; rg < 2; rg++) {
        int rw = row0 + w * 32 + rg * 16;
        uint mw[4];
        #pragma unroll
        for (int r = 0; r < 4; r++)
            mw[r] = mbt[((size_t)(b * TT + rw + 4 * hi + r)) * 16 + lo];
        float rsum[4] = {0.f, 0.f, 0.f, 0.f};
        #pragma unroll
        for (int c = 0; c < 4; c++) {
            int col = col0 + c * 16 + lo;
            int cg = by * 4 + c;
            #pragma unroll
            for (int r = 0; r < 4; r++) {
                float t2 = fast_tanh10(acc[rg][c][r] * 0.0625f);
                logitsB[((size_t)(b * TT + rw + 4 * hi + r)) * NN + col] = tr16(t2);
                rsum[r] += ((mw[r] >> cg) & 1u) ? __expf(t2 - 10.f) : 0.f;
            }
        }
        #pragma unroll
        for (int r = 0; r < 4; r++) {
            #pragma unroll
            for (int o = 1; o < 16; o <<= 1) rsum[r] += __shfl_xor(rsum[r], o);
        }
        if (lo == 0) {
            #pragma unroll
            for (int r = 0; r < 4; r++)
                psum[((size_t)(b * TT + rw + 4 * hi + r)) * 8 + by] = rsum[r];
        }
    }
}

// K5b: out = (mask ? logit : NEG_INF) - lse, lse = 10 + log(sum8 psum).
__global__ __launch_bounds__(256) void logits_fin_k(
    const ushort* __restrict__ logitsB, const float* __restrict__ psum,
    const uint* __restrict__ mbt, float* __restrict__ out) {
    int r0 = blockIdx.x * 8;
    int tid = threadIdx.x;
    __shared__ float lsev[8];
    __shared__ uint mwv[8][16];
    if (tid < 128) {
        mwv[tid >> 4][tid & 15] = mbt[(size_t)(r0 + (tid >> 4)) * 16 + (tid & 15)];
    } else if (tid < 136) {
        int rr = tid - 128;
        const float* pp = psum + (size_t)(r0 + rr) * 8;
        float s = 0.f;
        #pragma unroll
        for (int p = 0; p < 8; p++) s += pp[p];
        lsev[rr] = 10.f + __logf(fmaxf(s, 1e-37f));
    }
    __syncthreads();
    int row = tid >> 5, n0 = (tid & 31) * 16;
    float lse = lsev[row];
    const ushort* lb = logitsB + (size_t)(r0 + row) * NN + n0;
    bf16x8 v0 = *(const bf16x8*)(lb);
    bf16x8 v1 = *(const bf16x8*)(lb + 8);
    float ov[16];
    #pragma unroll
    for (int jj = 0; jj < 16; jj++) {
        int n = n0 + jj;
        uint bit = (mwv[row][n & 15] >> (n >> 4)) & 1u;
        float lv = bf2f((ushort)(jj < 8 ? v0[jj] : v1[jj - 8]));
        ov[jj] = bit ? lv - lse : NEG_INF - lse;
    }
    float* ob = out + (size_t)(r0 + row) * NN + n0;
    #pragma unroll
    for (int q = 0; q < 4; q++)
        *(float4*)(ob + q * 4) = *(float4*)(&ov[q * 4]);
}

// ---------------------------------------------------------------------------
extern "C" void kernel_launch(void* const* d_in, const int* in_sizes, int n_in,
                              void* d_out, int out_size, void* d_ws,
                              size_t ws_size, hipStream_t stream) {
    const float* emb = (const float*)d_in[0];
    const int* cur   = (const int*)d_in[1];
    const int* mask  = (const int*)d_in[2];
    const float* Wn  = (const float*)d_in[3];
    const float* Wf  = (const float*)d_in[4];
    const float* Ws  = (const float*)d_in[5];
    const float* Wo  = (const float*)d_in[6];
    float* out = (float*)d_out;

    const size_t SLABE = (size_t)BB * NN * DD;
    ushort* embB     = (ushort*)d_ws;
    ushort* gkT      = embB + SLABE;     // [bh][n][32]
    ushort* vTp      = gkT + SLABE;      // [bh][dh][n''] pre-permuted
    ushort* lkb      = vTp + SLABE;      // [b*N+n][256]
    ushort* gq       = lkb + SLABE;      // [b*T+t][256]
    ushort* headsB   = gq + SLABE;
    ushort* glimpseB = headsB + SLABE;
    ushort* WnT      = glimpseB + SLABE;
    ushort* WsT      = WnT + 768 * 256;
    ushort* WoT      = WsT + 256 * 256;
    uint*   mbt      = (uint*)(WoT + 256 * 256);
    float*  partial  = (float*)(mbt + (size_t)BB * TT * 16);
    // K5 scratch reuses embB/gkT/vTp region (dead after attn10):
    ushort* logitsB  = embB;                       // 16.8 MB
    float*  psum     = (float*)(embB + (size_t)BB * TT * NN);  // 512 KB

    prep_all_k<<<1600, 256, 0, stream>>>(emb, embB, partial, Wn, Ws, Wo,
                                         WnT, WsT, WoT, mask, mbt);
    // K1 (1536 blocks) + K2 (512 blocks) fused, XCD-chunked, async dbuf
    gemm3_k<0><<<2048, 256, 0, stream>>>(embB, WnT, WsT, gkT, vTp, lkb, gq,
                                         partial, Wf, cur);
    attn10_k<<<1024, 256, 0, stream>>>(gq, gkT, vTp, mbt, headsB);
    // K4, XCD-chunked, async dbuf
    gemm3_k<1><<<512, 256, 0, stream>>>(headsB, WoT, nullptr, glimpseB,
                                        nullptr, nullptr, nullptr, nullptr,
                                        nullptr, nullptr);
    // K5: two-pass pointer logits + log_softmax
    logits_mm_k<<<1024, 256, 0, stream>>>(glimpseB, lkb, mbt, logitsB, psum);
    logits_fin_k<<<BB * TT / 8, 256, 0, stream>>>(logitsB, psum, mbt, out);
}

// Round 17
// 101.387 us; speedup vs baseline: 1.3449x; 1.0106x over previous
//
#include <hip/hip_runtime.h>
#include <hip/hip_bf16.h>

constexpr int BB = 32;    // batch
constexpr int TT = 512;   // decode steps
constexpr int NN = 512;   // nodes
constexpr int DD = 256;   // model dim
constexpr int HH = 8;     // heads
constexpr int DH = 32;    // head dim
#define NEG_INF (-1e9f)

// scale folds (applied at producer epilogues):
// QSCL = 1/sqrt(32) * log2(e)  -> attn e = exp2(QK)
#define QSCL 0.25505872f
// LSCL = 0.0625 * 2 * log2(e)  -> logits tanh10 = 10 - 20/(exp2(y)+1)
#define LSCL 0.18033688f

typedef __attribute__((ext_vector_type(8))) short bf16x8;
typedef __attribute__((ext_vector_type(4))) float f32x4;

__device__ inline float ex2(float x) { return __builtin_amdgcn_exp2f(x); }

__device__ inline ushort f2bf(float x) {
    union { float f; unsigned u; } c; c.f = x;
    unsigned u = c.u + 0x7fffu + ((c.u >> 16) & 1u);  // RNE
    return (ushort)(u >> 16);
}
__device__ inline uint pk2t(float a, float b) {  // truncating pack
    return __builtin_amdgcn_perm(__float_as_uint(b), __float_as_uint(a),
                                 0x07060302u);
}
__device__ inline ushort tr16(float x) { return (ushort)(__float_as_uint(x) >> 16); }
__device__ inline float bf2f(ushort u) {
    union { uint u; float f; } c; c.u = (uint)u << 16; return c.f;
}
// async global->LDS, 16B/lane; dest = wave-uniform base + lane*16 (m97/m173)
__device__ inline void gload_lds16(const void* g, void* l) {
    __builtin_amdgcn_global_load_lds(
        (const __attribute__((address_space(1))) unsigned int*)g,
        (__attribute__((address_space(3))) unsigned int*)l, 16, 0, 0);
}

// ---------------------------------------------------------------------------
// prep_all: [0,256) emb cvt+partials | [256,576) weight transposes |
//           [576,1600) mask bit-pack
__global__ __launch_bounds__(256) void prep_all_k(
    const float* __restrict__ emb, ushort* __restrict__ embB,
    float* __restrict__ partial, const float* __restrict__ Wn,
    const float* __restrict__ Ws, const float* __restrict__ Wo,
    ushort* __restrict__ WnT, ushort* __restrict__ WsT,
    ushort* __restrict__ WoT, const int* __restrict__ mask,
    uint* __restrict__ mbt) {
    int j = blockIdx.x;
    int tid = threadIdx.x;
    if (j < 256) {
        int b = j >> 3, part = j & 7, d = tid;
        const float* eb = emb + ((size_t)b * NN + part * 64) * DD + d;
        ushort* ob = embB + ((size_t)b * NN + part * 64) * DD + d;
        float s = 0.f;
        #pragma unroll 4
        for (int i = 0; i < 64; i++) {
            float v = eb[(size_t)i * DD];
            s += v;
            ob[(size_t)i * DD] = f2bf(v);
        }
        partial[((size_t)b * 8 + part) * DD + d] = s;
    } else if (j < 576) {
        __shared__ float t[32][33];
        int g = j - 256;
        int gx = g % 40, gy = g / 40;
        const float* W;
        ushort* WT;
        int NC, xb;
        if (gx < 24)      { W = Wn; WT = WnT; NC = 768; xb = gx; }
        else if (gx < 32) { W = Ws; WT = WsT; NC = 256; xb = gx - 24; }
        else              { W = Wo; WT = WoT; NC = 256; xb = gx - 32; }
        int tx = tid & 31, ty = tid >> 5;
        int x = xb * 32 + tx;
        int y0 = gy * 32;
        #pragma unroll
        for (int i = 0; i < 4; i++)
            t[ty + i * 8][tx] = W[(size_t)(y0 + ty + i * 8) * NC + x];
        __syncthreads();
        #pragma unroll
        for (int i = 0; i < 4; i++)
            WT[(size_t)(xb * 32 + ty + i * 8) * 256 + y0 + tx] =
                f2bf(t[tx][ty + i * 8]);
    } else {
        int idx = (j - 576) * 256 + tid;
        int row = idx >> 4, w = idx & 15;
        const int* mr = mask + (size_t)row * NN + w;
        uint u = 0;
        #pragma unroll
        for (int c = 0; c < 32; c++) u |= (uint)(mr[c * 16] != 0) << c;
        mbt[idx] = u;
    }
}

// ---------------------------------------------------------------------------
// gemm3: BM=128 x BN=64 x BK=64, async-dbuf staging (verified r15).
// XCD-chunked. TASK 0: j<1536 K1 (proj; lk pre-scaled by LSCL);
//                j>=1536 K2 (gq = (emb[cur]@Ws + ctx)*QSCL, in-block ctx).
// TASK 1: K4 (glimpse = heads @ Wo).
template <int TASK>
__global__ __launch_bounds__(256) void gemm3_k(
    const ushort* __restrict__ A0, const ushort* __restrict__ WT0,
    const ushort* __restrict__ WT1, ushort* __restrict__ O0,
    ushort* __restrict__ O1, ushort* __restrict__ O2,
    ushort* __restrict__ O3, const float* __restrict__ partial,
    const float* __restrict__ Wf, const int* __restrict__ cur) {
    int j = blockIdx.x;
    bool k2 = (TASK == 0) && (j >= 1536);
    int bx, by;
    if (TASK == 0 && !k2) {
        int x = j & 7, t = j >> 3;           // t in [0,192)
        bx = x * 16 + t / 12; by = t % 12;
    } else {
        int jj = k2 ? j - 1536 : j;
        int x = jj & 7, t = jj >> 3;         // t in [0,64)
        bx = x * 16 + (t >> 2); by = t & 3;
    }
    int row0 = bx * 128, col0 = by * 64;
    int tid = threadIdx.x;
    int w = tid >> 6, l = tid & 63;
    int lo = l & 15, hi = l >> 4;

    __shared__ ushort As[2][128 * 64];  // 2 x 16KB
    __shared__ ushort Bs[2][64 * 64];   // 2 x 8KB
    __shared__ float ctxs[64];

    const ushort* WT = k2 ? WT1 : WT0;

    auto stage = [&](int buf, int kk) {
        #pragma unroll
        for (int i = 0; i < 4; i++) {
            int u = i * 256 + tid;
            int row = u >> 3, slot = u & 7;
            int arow = row0 + row;
            const ushort* ap;
            if (k2) {
                int b = arow >> 9;
                ap = A0 + ((size_t)(b * NN + cur[arow])) * DD;
            } else {
                ap = A0 + (size_t)arow * DD;
            }
            const void* gsrc = ap + kk * 64 + ((slot ^ (row & 7)) << 3);
            void* ldst = (char*)&As[buf][0] + i * 4096 + w * 1024;
            gload_lds16(gsrc, ldst);
        }
        #pragma unroll
        for (int i = 0; i < 2; i++) {
            int u = i * 256 + tid;
            int row = u >> 3, slot = u & 7;
            const void* gsrc =
                WT + (size_t)(col0 + row) * 256 + kk * 64 + ((slot ^ (row & 7)) << 3);
            void* ldst = (char*)&Bs[buf][0] + i * 4096 + w * 1024;
            gload_lds16(gsrc, ldst);
        }
    };

    const f32x4 zero = {0.f, 0.f, 0.f, 0.f};
    f32x4 acc[2][4] = {{zero, zero, zero, zero}, {zero, zero, zero, zero}};

    stage(0, 0);
    __syncthreads();
    #pragma unroll
    for (int kk = 0; kk < 4; kk++) {
        if (kk < 3) stage((kk + 1) & 1, kk + 1);
        int cb = kk & 1;
        #pragma unroll
        for (int ks = 0; ks < 2; ks++) {
            int sx = ((ks * 4 + hi) ^ (lo & 7)) << 4;
            bf16x8 af0 = *(const bf16x8*)((char*)&As[cb][0] + (w * 32 + lo) * 128 + sx);
            bf16x8 af1 = *(const bf16x8*)((char*)&As[cb][0] + (w * 32 + 16 + lo) * 128 + sx);
            #pragma unroll
            for (int c = 0; c < 4; c++) {
                bf16x8 bf = *(const bf16x8*)((char*)&Bs[cb][0] + (c * 16 + lo) * 128 + sx);
                acc[0][c] = __builtin_amdgcn_mfma_f32_16x16x32_bf16(af0, bf, acc[0][c], 0, 0, 0);
                acc[1][c] = __builtin_amdgcn_mfma_f32_16x16x32_bf16(af1, bf, acc[1][c], 0, 0, 0);
            }
        }
        __syncthreads();
    }

    int bbq = row0 >> 9;
    if (k2) {
        // in-block ctx: ctx[col] = (sum_p partial[b][p][:]/512) @ Wf[:, col]
        float* fs = (float*)&As[0][0];
        float mk = 0.f;
        #pragma unroll
        for (int p = 0; p < 8; p++)
            mk += partial[(size_t)bbq * 2048 + p * 256 + tid];
        fs[tid] = mk * (1.0f / 512.0f);
        __syncthreads();
        int cc = tid & 63, part = tid >> 6;
        float cs = 0.f;
        #pragma unroll 16
        for (int k = part * 64; k < part * 64 + 64; k++)
            cs += fs[k] * Wf[(size_t)k * 256 + col0 + cc];
        float* fs2 = fs + 256;
        fs2[part * 64 + cc] = cs;
        __syncthreads();
        if (tid < 64)
            ctxs[tid] = fs2[tid] + fs2[64 + tid] + fs2[128 + tid] + fs2[192 + tid];
        __syncthreads();
    }

    #pragma unroll
    for (int rg = 0; rg < 2; rg++) {
        int rw0 = row0 + w * 32 + rg * 16;
        int bb = rw0 >> 9;
        #pragma unroll
        for (int c = 0; c < 4; c++) {
            int col = col0 + c * 16 + lo;
            float v[4];
            #pragma unroll
            for (int r = 0; r < 4; r++) v[r] = acc[rg][c][r];
            if constexpr (TASK == 0) {
                if (k2) {
                    float bv = ctxs[col - col0];
                    #pragma unroll
                    for (int r = 0; r < 4; r++)
                        O3[(size_t)(rw0 + 4 * hi + r) * DD + col] =
                            f2bf((v[r] + bv) * QSCL);
                } else if (col < 256) {
                    int head = col >> 5, dh = col & 31;
                    #pragma unroll
                    for (int r = 0; r < 4; r++) {
                        int n = (rw0 + 4 * hi + r) & (NN - 1);
                        O0[(((size_t)(bb * HH + head) * NN + n) << 5) + dh] = f2bf(v[r]);
                    }
                } else if (col < 512) {
                    int cc2 = col - 256;
                    int bhv = bb * HH + (cc2 >> 5);
                    int dh = cc2 & 31;
                    int n0 = (rw0 + 4 * hi) & (NN - 1);
                    int m = n0 >> 2;
                    int p_ = m >> 3, s_ = (m >> 2) & 1, g_ = m & 3;
                    int n0p = (8 * p_ + 2 * g_ + s_) << 2;
                    ushort4 uv = {f2bf(v[0]), f2bf(v[1]), f2bf(v[2]), f2bf(v[3])};
                    *(ushort4*)(O1 + ((size_t)bhv * DH + dh) * NN + n0p) = uv;
                } else {
                    #pragma unroll
                    for (int r = 0; r < 4; r++)
                        O2[(size_t)(rw0 + 4 * hi + r) * 256 + (col - 512)] =
                            f2bf(v[r] * LSCL);
                }
            } else {
                #pragma unroll
                for (int r = 0; r < 4; r++)
                    O0[(size_t)(rw0 + 4 * hi + r) * DD + col] = f2bf(v[r]);
            }
        }
    }
}

// ---------------------------------------------------------------------------
// K3: two-phase LDS-staged swapped-operand attention, 128 q-rows/block,
// 4 blocks/CU (verified r14/r15). Q pre-scaled (exp2 direct), Q/mask
// hoisted across phases, setprio around MFMA clusters.
__global__ __launch_bounds__(256, 4) void attn11_k(
    const ushort* __restrict__ gq, const ushort* __restrict__ gkT,
    const ushort* __restrict__ vTp, const uint* __restrict__ mbt,
    ushort* __restrict__ headsB) {
    int j = blockIdx.x;
    int bh = j & 255, quarter = j >> 8;
    int b = bh >> 3, h = bh & 7;
    int tid = threadIdx.x;
    int w = tid >> 6, l = tid & 63;
    int lo = l & 15, hi = l >> 4;

    __shared__ ushort Ks[8192];       // 16KB: 256 n-rows x 64B, ^((n&7)<<4)
    __shared__ ushort Vs[8192];       // 16KB: 32 dh-rows x 512B, ^((dh&7)<<4)
    __shared__ ushort OT[4][16][40];  // 5KB transpose staging

    const f32x4 zero = {0.f, 0.f, 0.f, 0.f};
    const bf16x8 ones = {(short)0x3F80, (short)0x3F80, (short)0x3F80,
                         (short)0x3F80, (short)0x3F80, (short)0x3F80,
                         (short)0x3F80, (short)0x3F80};
    int q0 = quarter * 128;
    int kswz = (lo & 7) << 4;

    // hoisted Q fragments + mask words for both q-chunks (same both phases)
    bf16x8 qf0 = *(const bf16x8*)(gq + ((size_t)(b * TT + q0 + w * 16 + lo)) * DD + h * DH + hi * 8);
    bf16x8 qf1 = *(const bf16x8*)(gq + ((size_t)(b * TT + q0 + 64 + w * 16 + lo)) * DD + h * DH + hi * 8);
    uint4 mq0 = *(const uint4*)(mbt + ((size_t)(b * TT + q0 + w * 16 + lo)) * 16 + 4 * hi);
    uint4 mq1 = *(const uint4*)(mbt + ((size_t)(b * TT + q0 + 64 + w * 16 + lo)) * 16 + 4 * hi);

    f32x4 o0[2] = {zero, zero};
    f32x4 o1[2] = {zero, zero};
    f32x4 osum[2] = {zero, zero};

    const char* kbase = (const char*)(gkT + (size_t)bh * (NN * DH));
    const char* vbase = (const char*)(vTp + (size_t)bh * (DH * NN));

    for (int ph = 0; ph < 2; ph++) {
        if (ph) __syncthreads();
        {
            const char* ksrc = kbase + ph * 16384;
            #pragma unroll
            for (int i = 0; i < 4; i++) {
                int u = i * 256 + tid;
                int nn = u >> 2, slot = u & 3;
                uint4 v = *(const uint4*)(ksrc + nn * 64 + slot * 16);
                *(uint4*)((char*)Ks + ((nn * 64 + slot * 16) ^ ((nn & 7) << 4))) = v;
            }
        }
        {
            const char* vsrc = vbase + ph * 512;
            #pragma unroll
            for (int i = 0; i < 4; i++) {
                int u = i * 256 + tid;
                int dh = u >> 5, slot = u & 31;
                uint4 v = *(const uint4*)(vsrc + dh * 1024 + slot * 16);
                *(uint4*)((char*)Vs + ((dh * 512 + slot * 16) ^ ((dh & 7) << 4))) = v;
            }
        }
        __syncthreads();

        #pragma unroll
        for (int qc2 = 0; qc2 < 2; qc2++) {
            bf16x8 qf = qc2 ? qf1 : qf0;
            uint4 mq = qc2 ? mq1 : mq0;

            #pragma unroll 4
            for (int p = 0; p < 8; p++) {
                int nn = 32 * p + lo;
                bf16x8 kf0 = *(const bf16x8*)((char*)Ks + ((nn * 64 + hi * 16) ^ kswz));
                bf16x8 kf1 = *(const bf16x8*)((char*)Ks + (((nn + 16) * 64 + hi * 16) ^ kswz));
                __builtin_amdgcn_s_setprio(1);
                f32x4 s0 = __builtin_amdgcn_mfma_f32_16x16x32_bf16(kf0, qf, zero, 0, 0, 0);
                f32x4 s1 = __builtin_amdgcn_mfma_f32_16x16x32_bf16(kf1, qf, zero, 0, 0, 0);
                __builtin_amdgcn_s_setprio(0);
                union { bf16x8 v; uint u[4]; } pf;
                {
                    int c = ph * 16 + 2 * p;
                    float e0 = ((mq.x >> c) & 1u) ? ex2(s0[0]) : 0.f;
                    float e1 = ((mq.y >> c) & 1u) ? ex2(s0[1]) : 0.f;
                    float e2 = ((mq.z >> c) & 1u) ? ex2(s0[2]) : 0.f;
                    float e3 = ((mq.w >> c) & 1u) ? ex2(s0[3]) : 0.f;
                    pf.u[0] = pk2t(e0, e1);
                    pf.u[1] = pk2t(e2, e3);
                }
                {
                    int c = ph * 16 + 2 * p + 1;
                    float e0 = ((mq.x >> c) & 1u) ? ex2(s1[0]) : 0.f;
                    float e1 = ((mq.y >> c) & 1u) ? ex2(s1[1]) : 0.f;
                    float e2 = ((mq.z >> c) & 1u) ? ex2(s1[2]) : 0.f;
                    float e3 = ((mq.w >> c) & 1u) ? ex2(s1[3]) : 0.f;
                    pf.u[2] = pk2t(e0, e1);
                    pf.u[3] = pk2t(e2, e3);
                }
                int vo = (32 * p + 8 * hi) * 2;
                bf16x8 va0 = *(const bf16x8*)((char*)Vs + ((lo * 512 + vo) ^ kswz));
                bf16x8 va1 = *(const bf16x8*)((char*)Vs + (((lo + 16) * 512 + vo) ^ kswz));
                __builtin_amdgcn_s_setprio(1);
                o0[qc2] = __builtin_amdgcn_mfma_f32_16x16x32_bf16(va0, pf.v, o0[qc2], 0, 0, 0);
                o1[qc2] = __builtin_amdgcn_mfma_f32_16x16x32_bf16(va1, pf.v, o1[qc2], 0, 0, 0);
                osum[qc2] = __builtin_amdgcn_mfma_f32_16x16x32_bf16(ones, pf.v, osum[qc2], 0, 0, 0);
                __builtin_amdgcn_s_setprio(0);
            }
        }
    }

    #pragma unroll
    for (int qc2 = 0; qc2 < 2; qc2++) {
        int t0 = q0 + qc2 * 64 + w * 16;
        float inv = 1.0f / fmaxf(osum[qc2][0], 1e-30f);
        #pragma unroll
        for (int r = 0; r < 4; r++) {
            OT[w][lo][4 * hi + r] = tr16(o0[qc2][r] * inv);
            OT[w][lo][16 + 4 * hi + r] = tr16(o1[qc2][r] * inv);
        }
        bf16x8 ov = *(const bf16x8*)(&OT[w][lo][hi * 8]);
        *(bf16x8*)(headsB + ((size_t)(b * TT + t0 + lo)) * DD + h * DH + hi * 8) = ov;
    }
}

// ---------------------------------------------------------------------------
// K5a: pointer-logits GEMM (async dbuf, lk pre-scaled -> exp2 tanh).
// XCD-chunked: x=j&7 owns 4 batches.
__global__ __launch_bounds__(256) void logits_mm_k(
    const ushort* __restrict__ glimpse, const ushort* __restrict__ lkb,
    const uint* __restrict__ mbt, ushort* __restrict__ logitsB,
    float* __restrict__ psum) {
    int j = blockIdx.x;  // 1024
    int x = j & 7, t = j >> 3;
    int b = x * 4 + (t >> 5);
    int rem = t & 31;
    int bx = rem >> 3, by = rem & 7;
    int row0 = bx * 128, col0 = by * 64;
    int tid = threadIdx.x;
    int w = tid >> 6, l = tid & 63;
    int lo = l & 15, hi = l >> 4;

    __shared__ ushort As[2][128 * 64];
    __shared__ ushort Bs[2][64 * 64];

    const ushort* Abase = glimpse + (size_t)b * TT * DD;
    const ushort* Bbase = lkb + (size_t)b * NN * DD;

    auto stage = [&](int buf, int kk) {
        #pragma unroll
        for (int i = 0; i < 4; i++) {
            int u = i * 256 + tid;
            int row = u >> 3, slot = u & 7;
            const void* gsrc =
                Abase + (size_t)(row0 + row) * DD + kk * 64 + ((slot ^ (row & 7)) << 3);
            void* ldst = (char*)&As[buf][0] + i * 4096 + w * 1024;
            gload_lds16(gsrc, ldst);
        }
        #pragma unroll
        for (int i = 0; i < 2; i++) {
            int u = i * 256 + tid;
            int row = u >> 3, slot = u & 7;
            const void* gsrc =
                Bbase + (size_t)(col0 + row) * DD + kk * 64 + ((slot ^ (row & 7)) << 3);
            void* ldst = (char*)&Bs[buf][0] + i * 4096 + w * 1024;
            gload_lds16(gsrc, ldst);
        }
    };

    const f32x4 zero = {0.f, 0.f, 0.f, 0.f};
    f32x4 acc[2][4] = {{zero, zero, zero, zero}, {zero, zero, zero, zero}};

    stage(0, 0);
    __syncthreads();
    #pragma unroll
    for (int kk = 0; kk < 4; kk++) {
        if (kk < 3) stage((kk + 1) & 1, kk + 1);
        int cb = kk & 1;
        #pragma unroll
        for (int ks = 0; ks < 2; ks++) {
            int sx = ((ks * 4 + hi) ^ (lo & 7)) << 4;
            bf16x8 af0 = *(const bf16x8*)((char*)&As[cb][0] + (w * 32 + lo) * 128 + sx);
            bf16x8 af1 = *(const bf16x8*)((char*)&As[cb][0] + (w * 32 + 16 + lo) * 128 + sx);
            #pragma unroll
            for (int c = 0; c < 4; c++) {
                bf16x8 bf = *(const bf16x8*)((char*)&Bs[cb][0] + (c * 16 + lo) * 128 + sx);
                acc[0][c] = __builtin_amdgcn_mfma_f32_16x16x32_bf16(af0, bf, acc[0][c], 0, 0, 0);
                acc[1][c] = __builtin_amdgcn_mfma_f32_16x16x32_bf16(af1, bf, acc[1][c], 0, 0, 0);
            }
        }
        __syncthreads();
    }

    #pragma unroll
    for (int rg = 0; rg < 2; rg++) {
        int rw = row0 + w * 32 + rg * 16;
        uint mw[4];
        #pragma unroll
        for (int r = 0; r < 4; r++)
            mw[r] = mbt[((size_t)(b * TT + rw + 4 * hi + r)) * 16 + lo];
        float rsum[4] = {0.f, 0.f, 0.f, 0.f};
        #pragma unroll
        for (int c = 0; c < 4; c++) {
            int col = col0 + c * 16 + lo;
            int cg = by * 4 + c;
            #pragma unroll
            for (int r = 0; r < 4; r++) {
                // y pre-scaled by LSCL: tanh10 = 10 - 20/(exp2(y)+1)
                float y = fminf(fmaxf(acc[rg][c][r], -57.f), 57.f);
                float t2 = 10.f - 20.f / (ex2(y) + 1.f);
                logitsB[((size_t)(b * TT + rw + 4 * hi + r)) * NN + col] = tr16(t2);
                rsum[r] += ((mw[r] >> cg) & 1u) ? __expf(t2 - 10.f) : 0.f;
            }
        }
        #pragma unroll
        for (int r = 0; r < 4; r++) {
            #pragma unroll
            for (int o = 1; o < 16; o <<= 1) rsum[r] += __shfl_xor(rsum[r], o);
        }
        if (lo == 0) {
            #pragma unroll
            for (int r = 0; r < 4; r++)
                psum[((size_t)(b * TT + rw + 4 * hi + r)) * 8 + by] = rsum[r];
        }
    }
}

// K5b: out = (mask ? logit : NEG_INF) - lse, lse = 10 + log(sum8 psum).
__global__ __launch_bounds__(256) void logits_fin_k(
    const ushort* __restrict__ logitsB, const float* __restrict__ psum,
    const uint* __restrict__ mbt, float* __restrict__ out) {
    int r0 = blockIdx.x * 8;
    int tid = threadIdx.x;
    __shared__ float lsev[8];
    __shared__ uint mwv[8][16];
    if (tid < 128) {
        mwv[tid >> 4][tid & 15] = mbt[(size_t)(r0 + (tid >> 4)) * 16 + (tid & 15)];
    } else if (tid < 136) {
        int rr = tid - 128;
        const float* pp = psum + (size_t)(r0 + rr) * 8;
        float s = 0.f;
        #pragma unroll
        for (int p = 0; p < 8; p++) s += pp[p];
        lsev[rr] = 10.f + __logf(fmaxf(s, 1e-37f));
    }
    __syncthreads();
    int row = tid >> 5, n0 = (tid & 31) * 16;
    float lse = lsev[row];
    const ushort* lb = logitsB + (size_t)(r0 + row) * NN + n0;
    bf16x8 v0 = *(const bf16x8*)(lb);
    bf16x8 v1 = *(const bf16x8*)(lb + 8);
    float ov[16];
    #pragma unroll
    for (int jj = 0; jj < 16; jj++) {
        int n = n0 + jj;
        uint bit = (mwv[row][n & 15] >> (n >> 4)) & 1u;
        float lv = bf2f((ushort)(jj < 8 ? v0[jj] : v1[jj - 8]));
        ov[jj] = bit ? lv - lse : NEG_INF - lse;
    }
    float* ob = out + (size_t)(r0 + row) * NN + n0;
    #pragma unroll
    for (int q = 0; q < 4; q++)
        *(float4*)(ob + q * 4) = *(float4*)(&ov[q * 4]);
}

// ---------------------------------------------------------------------------
extern "C" void kernel_launch(void* const* d_in, const int* in_sizes, int n_in,
                              void* d_out, int out_size, void* d_ws,
                              size_t ws_size, hipStream_t stream) {
    const float* emb = (const float*)d_in[0];
    const int* cur   = (const int*)d_in[1];
    const int* mask  = (const int*)d_in[2];
    const float* Wn  = (const float*)d_in[3];
    const float* Wf  = (const float*)d_in[4];
    const float* Ws  = (const float*)d_in[5];
    const float* Wo  = (const float*)d_in[6];
    float* out = (float*)d_out;

    const size_t SLABE = (size_t)BB * NN * DD;
    ushort* embB     = (ushort*)d_ws;
    ushort* gkT      = embB + SLABE;     // [bh][n][32]
    ushort* vTp      = gkT + SLABE;      // [bh][dh][n''] pre-permuted
    ushort* lkb      = vTp + SLABE;      // [b*N+n][256], pre-scaled by LSCL
    ushort* gq       = lkb + SLABE;      // [b*T+t][256], pre-scaled by QSCL
    ushort* headsB   = gq + SLABE;
    ushort* glimpseB = headsB + SLABE;
    ushort* WnT      = glimpseB + SLABE;
    ushort* WsT      = WnT + 768 * 256;
    ushort* WoT      = WsT + 256 * 256;
    uint*   mbt      = (uint*)(WoT + 256 * 256);
    float*  partial  = (float*)(mbt + (size_t)BB * TT * 16);
    // K5 scratch reuses embB/gkT/vTp region (dead after attn11):
    ushort* logitsB  = embB;                       // 16.8 MB
    float*  psum     = (float*)(embB + (size_t)BB * TT * NN);  // 512 KB

    prep_all_k<<<1600, 256, 0, stream>>>(emb, embB, partial, Wn, Ws, Wo,
                                         WnT, WsT, WoT, mask, mbt);
    gemm3_k<0><<<2048, 256, 0, stream>>>(embB, WnT, WsT, gkT, vTp, lkb, gq,
                                         partial, Wf, cur);
    attn11_k<<<1024, 256, 0, stream>>>(gq, gkT, vTp, mbt, headsB);
    gemm3_k<1><<<512, 256, 0, stream>>>(headsB, WoT, nullptr, glimpseB,
                                        nullptr, nullptr, nullptr, nullptr,
                                        nullptr, nullptr);
    logits_mm_k<<<1024, 256, 0, stream>>>(glimpseB, lkb, mbt, logitsB, psum);
    logits_fin_k<<<BB * TT / 8, 256, 0, stream>>>(logitsB, psum, mbt, out);
}